// Round 3
// baseline (9113.393 us; speedup 1.0000x reference)
//
#include <hip/hip_runtime.h>
#include <hip/hip_bf16.h>

// ---------------------------------------------------------------------------
// MA_LSTM on MI355X (gfx950) — persistent kernel, v3: fence-free coherence.
// v2 post-mortem: __threadfence() = buffer_wbl2/buffer_inv (full 4MB L2 flash
// ops) x ~80 per XCD per step dominated (68us/step, MfmaUtil 2%). v3 removes
// ALL fences: every cross-block datum moves via relaxed AGENT-scope atomics
// (sc1 -> coherence point / L3), the same mechanism the v2 flags already used
// successfully. Signal = __syncthreads (drains vmcnt) + lane0 flag store.
//   blocks 0..159 ("A"): z-GEMM partials (40 col-groups x 4 K-quarters),
//       weights LDS-resident; h/c read via sc1 atomics, 3-deep prefetch.
//   blocks 160..223 ("B"): gates (1 row) + agg-GEMM (16 u-cols) + state.
// 3 cross-block hops/step: fA (z ready) -> fB (O ready) -> fC (state ready).
// ---------------------------------------------------------------------------

typedef short  bf16x8 __attribute__((ext_vector_type(8)));
typedef float  f32x4  __attribute__((ext_vector_type(4)));
typedef __hip_bfloat16 bf16;
typedef unsigned long long u64;

#define U 1024
#define BATCH 64
#define TSTEPS 128
#define DIM 256
#define N5 5120
#define K2 2048   // h(1024) + c(1024)

// ---- workspace layout (bytes) ----
#define OFF_WRC   0u                       // bf16 [5120][2048]  (Wr^T | Wc^T)
#define OFF_KT    20971520u                // bf16 [5120][256]   kernel^T
#define OFF_AGGT  23592960u                // bf16 [1024][3072]  aggregation^T
#define OFF_XBF   29884416u                // bf16 [64][128][256] x in bf16
#define OFF_ZP    34078720u                // f32  [4][64][5120] z partials
#define OFF_ABUF  39321600u                // bf16 [4][64][1024] h_hi,h_lo,c_hi,c_lo
#define OFF_C32   39845888u                // f32  [64 blocks][64 rows][16] block-private
#define OFF_OBUF  40108032u                // bf16 [64][3072]
#define OFF_SCAL  40501248u                // f32  [8]
#define OFF_CTR   40501504u                // int flags (12KB zone, 32B-padded)

#define NBLK_A 160
#define NBLK_B 64
#define NBLK   224
#define FPAD   8      // ints between flags (32B) — fewer pollers per line

#define RS_B 6144     // LDS row stride bytes, B-role aggT: 3072 bf16
#define KT_OFF 131072 // LDS byte offset of kt slab in A-role

#define MFMA16(a,b,c) __builtin_amdgcn_mfma_f32_16x16x32_bf16((a),(b),(c),0,0,0)

// ---------------------------------------------------------------------------
__global__ __launch_bounds__(256) void k_xconv(const float* __restrict__ in,
                                               bf16* __restrict__ o, int n4) {
    const int i = blockIdx.x * 256 + threadIdx.x;
    if (i < n4) {
        const float4 v = ((const float4*)in)[i];
        bf16 tmp[4] = {__float2bfloat16(v.x), __float2bfloat16(v.y),
                       __float2bfloat16(v.z), __float2bfloat16(v.w)};
        ((uint2*)o)[i] = *(const uint2*)tmp;
    }
}

// ---------------------------------------------------------------------------
__global__ __launch_bounds__(256) void k_transpose(const float* __restrict__ in,
                                                   bf16* __restrict__ out,
                                                   int C, int out_stride, int out_off) {
    __shared__ bf16 tile[64][65];
    const int tc = blockIdx.x * 64, tr = blockIdx.y * 64;
    const int tx = threadIdx.x & 63, ty0 = threadIdx.x >> 6;
#pragma unroll
    for (int i = 0; i < 64; i += 4)
        tile[ty0 + i][tx] = __float2bfloat16(in[(tr + ty0 + i) * C + tc + tx]);
    __syncthreads();
#pragma unroll
    for (int i = 0; i < 64; i += 4)
        out[(tc + ty0 + i) * out_stride + out_off + tr + tx] = tile[tx][ty0 + i];
}

// ---------------------------------------------------------------------------
struct AttPtrs { const float* p[12]; };

__global__ __launch_bounds__(256) void k_scal(AttPtrs ap, float* __restrict__ scal) {
    __shared__ float red[256];
    const int tid = threadIdx.x;
    for (int q = 0; q < 6; ++q) {
        const float* l = ap.p[2 * q];
        const float* r = ap.p[2 * q + 1];
        float s = 0.f;
        for (int i = tid; i < 1024; i += 256)
            s += l[i] * r[i];
        red[tid] = s; __syncthreads();
        for (int o = 128; o > 0; o >>= 1) {
            if (tid < o) red[tid] += red[tid + o];
            __syncthreads();
        }
        if (tid == 0) scal[q] = red[0];
        __syncthreads();
    }
}

// ---------------------------------------------------------------------------
// block collectives (256 threads = 4 waves)
__device__ __forceinline__ float wave_sum(float v) {
#pragma unroll
    for (int o = 32; o > 0; o >>= 1) v += __shfl_xor(v, o, 64);
    return v;
}
__device__ __forceinline__ float wave_max(float v) {
#pragma unroll
    for (int o = 32; o > 0; o >>= 1) v = fmaxf(v, __shfl_xor(v, o, 64));
    return v;
}
__device__ __forceinline__ float wave_scan(float v, int lane) {
#pragma unroll
    for (int o = 1; o < 64; o <<= 1) {
        float n = __shfl_up(v, o, 64);
        if (lane >= o) v += n;
    }
    return v;
}
__device__ __forceinline__ float block_sum(float v, float* sm4, int w, int lane) {
    float s = wave_sum(v);
    if (lane == 0) sm4[w] = s;
    __syncthreads();
    float r = sm4[0] + sm4[1] + sm4[2] + sm4[3];
    __syncthreads();
    return r;
}
__device__ __forceinline__ float block_max(float v, float* sm4, int w, int lane) {
    float s = wave_max(v);
    if (lane == 0) sm4[w] = s;
    __syncthreads();
    float r = fmaxf(fmaxf(sm4[0], sm4[1]), fmaxf(sm4[2], sm4[3]));
    __syncthreads();
    return r;
}
__device__ __forceinline__ float block_scan(float v, float* sm4, int w, int lane, float* total) {
    float ws = wave_scan(v, lane);
    if (lane == 63) sm4[w] = ws;
    __syncthreads();
    float base = 0.f;
    if (w > 0) base += sm4[0];
    if (w > 1) base += sm4[1];
    if (w > 2) base += sm4[2];
    *total = sm4[0] + sm4[1] + sm4[2] + sm4[3];
    __syncthreads();
    return base + ws;
}
__device__ __forceinline__ float sigm(float x) { return 1.f / (1.f + __expf(-x)); }

// ---------------------------------------------------------------------------
// sc1 (coherence-point) data path: relaxed agent-scope atomics. These bypass
// the non-coherent per-XCD L2 — proven by v2's flags, which poll successfully
// across XCDs with exactly this mechanism and no fence.
__device__ __forceinline__ u64 ald64(const void* p) {
    return __hip_atomic_load((const u64*)p, __ATOMIC_RELAXED, __HIP_MEMORY_SCOPE_AGENT);
}
__device__ __forceinline__ bf16x8 ald16B(const bf16* p) {
    union { bf16x8 v; u64 u[2]; } r;
    r.u[0] = ald64(p);
    r.u[1] = ald64((const char*)p + 8);
    return r.v;
}
__device__ __forceinline__ f32x4 ald_f4(const float* p) {
    union { f32x4 v; u64 u[2]; } r;
    r.u[0] = ald64(p);
    r.u[1] = ald64(p + 2);
    return r.v;
}
__device__ __forceinline__ float ald_f(const float* p) {
    return __hip_atomic_load(p, __ATOMIC_RELAXED, __HIP_MEMORY_SCOPE_AGENT);
}
__device__ __forceinline__ void ast64(void* p, u64 v) {
    __hip_atomic_store((u64*)p, v, __ATOMIC_RELAXED, __HIP_MEMORY_SCOPE_AGENT);
}
__device__ __forceinline__ void ast32(void* p, unsigned v) {
    __hip_atomic_store((unsigned*)p, v, __ATOMIC_RELAXED, __HIP_MEMORY_SCOPE_AGENT);
}
__device__ __forceinline__ void ast_f(float* p, float v) {
    __hip_atomic_store(p, v, __ATOMIC_RELAXED, __HIP_MEMORY_SCOPE_AGENT);
}
__device__ __forceinline__ unsigned bfbits(bf16 h) {
    unsigned short s; __builtin_memcpy(&s, &h, 2); return (unsigned)s;
}

// flag barriers, fence-free:
// signal: __syncthreads() — hipcc emits s_waitcnt vmcnt(0) before s_barrier,
//         so every thread's sc1 data stores are at the coherence point — then
//         lane0 stores the flag (sc1). Visibility order guaranteed.
// wait:   wave0 polls sc1 loads; no fence needed (data reads are sc1 too).
__device__ __forceinline__ void signal_flag(int* f, int v) {
    __syncthreads();
    if (threadIdx.x == 0)
        __hip_atomic_store(f, v, __ATOMIC_RELAXED, __HIP_MEMORY_SCOPE_AGENT);
}
__device__ __forceinline__ void wait_ge(const int* f, int n, int tgt) {
    if (threadIdx.x < 64) {
        for (;;) {
            int mn = 0x7fffffff;
            for (int i = threadIdx.x; i < n; i += 64) {
                const int v = __hip_atomic_load(f + i * FPAD, __ATOMIC_RELAXED,
                                                __HIP_MEMORY_SCOPE_AGENT);
                mn = v < mn ? v : mn;
            }
            if (__all(mn >= tgt)) break;
            __builtin_amdgcn_s_sleep(1);
        }
    }
    __syncthreads();
}

// swizzled LDS read (XOR (row&7)<<4 spreads stride-pow2 rows over 8 16B slots)
__device__ __forceinline__ bf16x8 lds_rd(const char* s, int nloc, int kb, int rs) {
    return *(const bf16x8*)(s + nloc * rs + (kb ^ ((nloc & 7) << 4)));
}

// ---------------------------------------------------------------------------
__global__ __launch_bounds__(256, 1) void k_persist(
    const bf16* __restrict__ xbf, const bf16* __restrict__ kt,
    const bf16* __restrict__ wrct, const bf16* __restrict__ aggt,
    float* __restrict__ zp, bf16* __restrict__ abuf,
    float* __restrict__ c32, bf16* __restrict__ obuf,
    const float* __restrict__ scal, const float* __restrict__ bias,
    float* __restrict__ out, int* __restrict__ ctr)
{
    __shared__ __align__(16) char smem[147456];   // A: 128KB weights + 16KB kt
    __shared__ float sm4[4];

    const int bid = blockIdx.x, tid = threadIdx.x;
    const int w = tid >> 6, lane = tid & 63;
    const int ml = lane & 15, q = lane >> 4;
    int* fA = ctr;            // [160*FPAD] z-partials ready (value t+1)
    int* fB = ctr + 1280;     // [64*FPAD]  O rows ready
    int* fC = ctr + 1792;     // [64*FPAD]  h,c state ready

    if (bid < NBLK_A) {
        // =================== role A: z-GEMM partial ====================
        const int cg = bid >> 2;            // col group: cols cg*128..+127
        const int kq = bid & 3;             // K quarter: 0,1=h halves; 2,3=c halves
        const int n0 = cg * 128;
        const int kwbase = (kq < 2) ? kq * 512 : 1024 + (kq - 2) * 512;
        const int kA0 = (kq & 1) * 512;     // offset within h (or c) plane

        // stage weights [128][512] bf16, swizzled, rs=1024B
        for (int i = 0; i < 32; ++i) {
            const int cid = i * 256 + tid;
            const int row = cid >> 6, k = (cid & 63) * 8;
            bf16x8 v = *(const bf16x8*)(wrct + (size_t)(n0 + row) * K2 + kwbase + k);
            *(bf16x8*)(smem + row * 1024 + ((k * 2) ^ ((row & 7) << 4))) = v;
        }
        // stage kt slab [128][64] bf16, swizzled, rs=128B
        for (int i = 0; i < 4; ++i) {
            const int cid = i * 256 + tid;
            const int row = cid >> 3, k = (cid & 7) * 8;
            bf16x8 v = *(const bf16x8*)(kt + (size_t)(n0 + row) * DIM + kq * 64 + k);
            *(bf16x8*)(smem + KT_OFF + row * 128 + ((k * 2) ^ ((row & 7) << 4))) = v;
        }
        __syncthreads();

        const bf16* hiP = abuf + (kq < 2 ? 0 : 2) * 65536;
        const bf16* loP = abuf + (kq < 2 ? 1 : 3) * 65536;
        const int rowLDS0 = w * 32 + ml;       // this wave's LDS B rows
        float* zpq = zp + (size_t)kq * 64 * N5;
        const int colA = n0 + w * 32 + ml;
        const int colB = colA + 16;

#define LOADC(C, B) do { _Pragma("unroll") \
        for (int mi_ = 0; mi_ < 4; ++mi_) { \
            const int off_ = (mi_ * 16 + ml) * U + kA0 + (C) * 32 + q * 8; \
            ah[B][mi_] = ald16B(hiP + off_); \
            al[B][mi_] = ald16B(loP + off_); \
        } } while (0)

        for (int t = 0; t < TSTEPS; ++t) {
            f32x4 acc[8];
#pragma unroll
            for (int i = 0; i < 8; ++i) acc[i] = (f32x4){0.f, 0.f, 0.f, 0.f};

            // ---- x @ kernel slice (64 K per quarter): independent of state
#pragma unroll
            for (int cx = 0; cx < 2; ++cx) {
                const int kx = kq * 64 + cx * 32 + q * 8;
                bf16x8 ax[4];
#pragma unroll
                for (int mi = 0; mi < 4; ++mi)
                    ax[mi] = *(const bf16x8*)(xbf + ((size_t)(mi * 16 + ml) * TSTEPS + t) * DIM + kx);
                const bf16x8 b0 = lds_rd(smem + KT_OFF, rowLDS0, cx * 64 + q * 16, 128);
                const bf16x8 b1 = lds_rd(smem + KT_OFF, rowLDS0 + 16, cx * 64 + q * 16, 128);
#pragma unroll
                for (int mi = 0; mi < 4; ++mi) {
                    acc[mi * 2 + 0] = MFMA16(ax[mi], b0, acc[mi * 2 + 0]);
                    acc[mi * 2 + 1] = MFMA16(ax[mi], b1, acc[mi * 2 + 1]);
                }
            }

            wait_ge(fC, NBLK_B, t);          // state of step t-1 ready

            // ---- (h|c) quarter, hi+lo: 16 k-chunks, 3-deep prefetch
            {
                bf16x8 ah[4][4], al[4][4];
                LOADC(0, 0);
                LOADC(1, 1);
                LOADC(2, 2);
#pragma unroll
                for (int ch = 0; ch < 16; ++ch) {
                    if (ch < 13) LOADC(ch + 3, (ch + 3) & 3);
                    const bf16x8 b0 = lds_rd(smem, rowLDS0, ch * 64 + q * 16, 1024);
                    const bf16x8 b1 = lds_rd(smem, rowLDS0 + 16, ch * 64 + q * 16, 1024);
                    const int B_ = ch & 3;
#pragma unroll
                    for (int mi = 0; mi < 4; ++mi) {
                        acc[mi * 2 + 0] = MFMA16(ah[B_][mi], b0, acc[mi * 2 + 0]);
                        acc[mi * 2 + 1] = MFMA16(ah[B_][mi], b1, acc[mi * 2 + 1]);
                        acc[mi * 2 + 0] = MFMA16(al[B_][mi], b0, acc[mi * 2 + 0]);
                        acc[mi * 2 + 1] = MFMA16(al[B_][mi], b1, acc[mi * 2 + 1]);
                    }
                }
            }

            // ---- epilogue: write partial z via sc1 stores (bias on B side)
#pragma unroll
            for (int mi = 0; mi < 4; ++mi)
#pragma unroll
                for (int r = 0; r < 4; ++r) {
                    const int row = mi * 16 + q * 4 + r;
                    ast_f(&zpq[row * N5 + colA], acc[mi * 2 + 0][r]);
                    ast_f(&zpq[row * N5 + colB], acc[mi * 2 + 1][r]);
                }
            signal_flag(fA + bid * FPAD, t + 1);
        }
#undef LOADC
    } else {
        // ========= role B: gates (row rb) + agg-GEMM (16 u-cols) + state =========
        const int rb = bid - NBLK_A;
        const int n0b = rb * 16;
        // stage aggT tile [16][3072] bf16, swizzled, rs=6144B
        for (int i = 0; i < 24; ++i) {
            const int cid = i * 256 + tid;
            const int nloc = cid / 384, kc = cid - nloc * 384;
            const int k = kc * 8;
            bf16x8 v = *(const bf16x8*)(aggt + (size_t)(n0b + nloc) * 3072 + k);
            *(bf16x8*)(smem + nloc * RS_B + ((k * 2) ^ ((nloc & 7) << 4))) = v;
        }
        __syncthreads();

        const float s_ud = scal[0], s_ur = scal[1], s_ru = scal[2],
                    s_rd = scal[3], s_du = scal[4], s_dr = scal[5];
        const int rowA = w * 16 + ml;
        const bf16* orow = obuf + rowA * 3072;
        float* cpriv = c32 + rb * 1024;      // block-private [64 rows][16]

#define LOADO(G, BUF) do { _Pragma("unroll") \
        for (int j_ = 0; j_ < 8; ++j_) \
            ob[BUF][j_] = ald16B(orow + ((G) * 8 + j_) * 32 + q * 8); \
        } while (0)

        for (int t = 0; t < TSTEPS; ++t) {
            wait_ge(fA, NBLK_A, t + 1);      // all z partials of step t ready
            // ---------------- P2: gates for batch row rb ----------------
            {
                f32x4 zu = {0.f,0.f,0.f,0.f}, zd = {0.f,0.f,0.f,0.f}, zn = {0.f,0.f,0.f,0.f};
#pragma unroll
                for (int kqi = 0; kqi < 4; ++kqi) {
                    const float* bp = zp + (size_t)kqi * 64 * N5 + rb * N5;
                    zu += ald_f4(bp + tid * 4);
                    zd += ald_f4(bp + U + tid * 4);
                    zn += ald_f4(bp + 2 * U + tid * 4);
                }
                zu += ((const f32x4*)bias)[tid];
                zd += ((const f32x4*)(bias + U))[tid];
                zn += ((const f32x4*)(bias + 2 * U))[tid];

                float mup = block_max(fmaxf(fmaxf(zu[0], zu[1]), fmaxf(zu[2], zu[3])), sm4, w, lane);
                const float e0 = __expf(zu[0] - mup), e1 = __expf(zu[1] - mup),
                            e2 = __expf(zu[2] - mup), e3 = __expf(zu[3] - mup);
                float totu;
                float inclu = block_scan(e0 + e1 + e2 + e3, sm4, w, lane, &totu);
                const float exclu = inclu - (e0 + e1 + e2 + e3);
                const float inv_u = 1.f / totu;
                const float u0 = (exclu + e0) * inv_u;
                const float u1 = (exclu + e0 + e1) * inv_u;
                const float u2 = (exclu + e0 + e1 + e2) * inv_u;
                const float u3 = (exclu + e0 + e1 + e2 + e3) * inv_u;

                float mdn = block_max(fmaxf(fmaxf(zd[0], zd[1]), fmaxf(zd[2], zd[3])), sm4, w, lane);
                const float f0 = __expf(zd[0] - mdn), f1 = __expf(zd[1] - mdn),
                            f2 = __expf(zd[2] - mdn), f3 = __expf(zd[3] - mdn);
                float totd;
                float incld = block_scan(f0 + f1 + f2 + f3, sm4, w, lane, &totd);
                const float excld = incld - (f0 + f1 + f2 + f3);
                const float inv_d = 1.f / totd;
                const float d0 = (totd - excld) * inv_d;
                const float d1 = (totd - excld - f0) * inv_d;
                const float d2 = (totd - excld - f0 - f1) * inv_d;
                const float d3 = (totd - excld - f0 - f1 - f2) * inv_d;

                const float du = block_sum(d0 * u0 + d1 * u1 + d2 * u2 + d3 * u3, sm4, w, lane);
                const float ru = block_sum(zn[0] * u0 + zn[1] * u1 + zn[2] * u2 + zn[3] * u3, sm4, w, lane);
                const float dr = block_sum(d0 * zn[0] + d1 * zn[1] + d2 * zn[2] + d3 * zn[3], sm4, w, lane);

                bf16* orw = obuf + rb * 3072;
                const int j0 = tid * 4;
                const float uu[4] = {u0, u1, u2, u3};
                const float dd[4] = {d0, d1, d2, d3};
                const float rr[4] = {zn[0], zn[1], zn[2], zn[3]};
                union { bf16 h[4]; u64 u; } p1, p2, p3;
#pragma unroll
                for (int i = 0; i < 4; ++i) {
                    p1.h[i] = __float2bfloat16(sigm(s_ud * uu[i] * du) + sigm(s_ur * uu[i] * ru));
                    p2.h[i] = __float2bfloat16(sigm(s_ru * rr[i] * ru) + sigm(s_rd * rr[i] * dr));
                    p3.h[i] = __float2bfloat16(sigm(s_du * dd[i] * du) + sigm(s_dr * dd[i] * dr));
                }
                ast64(orw + j0,         p1.u);
                ast64(orw + U + j0,     p2.u);
                ast64(orw + 2 * U + j0, p3.u);
            }
            signal_flag(fB + rb * FPAD, t + 1);

            // hoisted z3/z4 (depends only on fA): loads fly during fB wait
            float z3v[4], z4v[4];
            {
                const int col = n0b + ml;
                const int r0 = w * 16 + q * 4;
#pragma unroll
                for (int r = 0; r < 4; ++r) {
                    z3v[r] = bias[3 * U + col];
                    z4v[r] = bias[4 * U + col];
#pragma unroll
                    for (int kqi = 0; kqi < 4; ++kqi) {
                        const float* zr = zp + (size_t)kqi * 64 * N5 + (size_t)(r0 + r) * N5;
                        z3v[r] += ald_f(zr + 3 * U + col);
                        z4v[r] += ald_f(zr + 4 * U + col);
                    }
                }
            }
            wait_ge(fB, NBLK_B, t + 1);      // all O rows ready
            // -------- P3: f = sigm(O@agg); state update; emit out --------
            {
                f32x4 p0 = {0.f, 0.f, 0.f, 0.f}, p1 = {0.f, 0.f, 0.f, 0.f};
                bf16x8 ob[4][8];
                LOADO(0, 0);
                LOADO(1, 1);
                LOADO(2, 2);
#pragma unroll
                for (int g = 0; g < 12; ++g) {
                    if (g < 9) LOADO(g + 3, (g + 3) & 3);
#pragma unroll
                    for (int j = 0; j < 8; ++j) {
                        const int ch = g * 8 + j;
                        const int kb = ch * 64 + q * 16;
                        const bf16x8 b = lds_rd(smem, ml, kb, RS_B);
                        if (j & 1) p1 = MFMA16(ob[g & 3][j], b, p1);
                        else       p0 = MFMA16(ob[g & 3][j], b, p0);
                    }
                }
                const f32x4 accv = p0 + p1;
                const int col = n0b + ml;
                const int r0 = w * 16 + q * 4;
#pragma unroll
                for (int r = 0; r < 4; ++r) {
                    const int row = r0 + r;
                    const float f = sigm(accv[r]);
                    const float cold = cpriv[row * 16 + ml];
                    const float cn = f * cold + (1.f - f) * tanhf(z4v[r]);
                    const float hn = z3v[r] * tanhf(cn);
                    cpriv[row * 16 + ml] = cn;
                    const bf16 chb = __float2bfloat16(cn);
                    const bf16 clb = __float2bfloat16(cn - __bfloat162float(chb));
                    const bf16 hhb = __float2bfloat16(hn);
                    const bf16 hlb = __float2bfloat16(hn - __bfloat162float(hhb));
                    // pack lane-pairs (cols col,col+1) into 32-bit sc1 stores
                    unsigned vh = bfbits(hhb), vl = bfbits(hlb),
                             vc = bfbits(chb), vx = bfbits(clb);
                    const unsigned ph = (unsigned)__shfl_xor((int)vh, 1, 64);
                    const unsigned pl = (unsigned)__shfl_xor((int)vl, 1, 64);
                    const unsigned pc = (unsigned)__shfl_xor((int)vc, 1, 64);
                    const unsigned px = (unsigned)__shfl_xor((int)vx, 1, 64);
                    if (!(ml & 1)) {
                        const int eo = row * U + col;
                        ast32((unsigned*)(abuf + 0 * 65536 + eo), vh | (ph << 16));
                        ast32((unsigned*)(abuf + 1 * 65536 + eo), vl | (pl << 16));
                        ast32((unsigned*)(abuf + 2 * 65536 + eo), vc | (pc << 16));
                        ast32((unsigned*)(abuf + 3 * 65536 + eo), vx | (px << 16));
                    }
                    out[((size_t)row * TSTEPS + t) * U + col] = hn;
                }
            }
            signal_flag(fC + rb * FPAD, t + 1);
        }
#undef LOADO
    }
}

// ---------------------------------------------------------------------------
extern "C" void kernel_launch(void* const* d_in, const int* in_sizes, int n_in,
                              void* d_out, int out_size, void* d_ws, size_t ws_size,
                              hipStream_t stream) {
    (void)in_sizes; (void)n_in; (void)out_size; (void)ws_size;
    const float* x    = (const float*)d_in[0];
    const float* Wk   = (const float*)d_in[1];   // (256,5120)
    const float* Wr   = (const float*)d_in[2];   // (1024,5120)
    const float* Wc   = (const float*)d_in[3];   // (1024,5120)
    const float* bias = (const float*)d_in[4];   // (5120)
    const float* agg  = (const float*)d_in[5];   // (3072,1024)

    char* ws = (char*)d_ws;
    bf16*  wrct = (bf16*)(ws + OFF_WRC);
    bf16*  kt   = (bf16*)(ws + OFF_KT);
    bf16*  aggt = (bf16*)(ws + OFF_AGGT);
    bf16*  xbf  = (bf16*)(ws + OFF_XBF);
    float* zp   = (float*)(ws + OFF_ZP);
    bf16*  abuf = (bf16*)(ws + OFF_ABUF);
    float* c32  = (float*)(ws + OFF_C32);
    bf16*  obuf = (bf16*)(ws + OFF_OBUF);
    float* scal = (float*)(ws + OFF_SCAL);
    int*   ctr  = (int*)(ws + OFF_CTR);
    float* out  = (float*)d_out;

    hipMemsetAsync(abuf, 0, 4 * 65536 * sizeof(bf16), stream);
    hipMemsetAsync(c32, 0, BATCH * U * sizeof(float), stream);
    hipMemsetAsync(ctr, 0, 12288, stream);   // flag zone reset each launch

    // one-time conversions / transposes
    k_xconv<<<(BATCH * TSTEPS * DIM / 4 + 255) / 256, 256, 0, stream>>>(x, xbf, BATCH * TSTEPS * DIM / 4);
    k_transpose<<<dim3(5120 / 64, 1024 / 64), 256, 0, stream>>>(Wr, wrct, 5120, 2048, 0);
    k_transpose<<<dim3(5120 / 64, 1024 / 64), 256, 0, stream>>>(Wc, wrct, 5120, 2048, 1024);
    k_transpose<<<dim3(5120 / 64, 256 / 64),  256, 0, stream>>>(Wk, kt,   5120, 256, 0);
    k_transpose<<<dim3(1024 / 64, 3072 / 64), 256, 0, stream>>>(agg, aggt, 1024, 3072, 0);

    AttPtrs ap;
    for (int i = 0; i < 12; ++i) ap.p[i] = (const float*)d_in[6 + i];
    k_scal<<<1, 256, 0, stream>>>(ap, scal);

    // the whole recurrence: one persistent launch
    k_persist<<<NBLK, 256, 0, stream>>>(xbf, kt, wrct, aggt, zp, abuf, c32,
                                        obuf, scal, bias, out, ctr);
}

// Round 5
// 6577.618 us; speedup vs baseline: 1.3855x; 1.3855x over previous
//
#include <hip/hip_runtime.h>
#include <hip/hip_bf16.h>

// ---------------------------------------------------------------------------
// MA_LSTM on MI355X (gfx950) — persistent kernel, v5.
// v4 post-mortem: 3-deep prefetch ring with distance-3 clobbered the buffer
// being consumed (LOADG(g+3,(g+3)%3) == consume g%3) -> wrong h/c operands for
// 5/8 of K -> absmax 0.55. v5: 4-deep ring (load (g+3)&3, consume g&3), same
// as v3's verified A-loop and the (correct) P3 loop.
// Structure (v4): A-wave = 16-row group x all 128 cols -> duplication-free
// h/c loads (128 KB/block/step, 4x less sc1 traffic than v3).
//   blocks 0..159 ("A"): z-GEMM partials (40 col-groups x 4 K-quarters).
//   blocks 160..223 ("B"): gates (1 row) + agg-GEMM (16 u-cols) + state.
// Fence-free: cross-block data via relaxed AGENT-scope atomics (sc1).
// ---------------------------------------------------------------------------

typedef short  bf16x8 __attribute__((ext_vector_type(8)));
typedef float  f32x4  __attribute__((ext_vector_type(4)));
typedef __hip_bfloat16 bf16;
typedef unsigned long long u64;

#define U 1024
#define BATCH 64
#define TSTEPS 128
#define DIM 256
#define N5 5120
#define K2 2048   // h(1024) + c(1024)

// ---- workspace layout (bytes) ----
#define OFF_WRC   0u                       // bf16 [5120][2048]  (Wr^T | Wc^T)
#define OFF_KT    20971520u                // bf16 [5120][256]   kernel^T
#define OFF_AGGT  23592960u                // bf16 [1024][3072]  aggregation^T
#define OFF_XBF   29884416u                // bf16 [64][128][256] x in bf16
#define OFF_ZP    34078720u                // f32  [4][64][5120] z partials
#define OFF_ABUF  39321600u                // bf16 [4][64][1024] h_hi,h_lo,c_hi,c_lo
#define OFF_C32   39845888u                // f32  [64 blocks][64 rows][16] block-private
#define OFF_OBUF  40108032u                // bf16 [64][3072]
#define OFF_SCAL  40501248u                // f32  [8]
#define OFF_CTR   40501504u                // int flags (12KB zone, 32B-padded)

#define NBLK_A 160
#define NBLK_B 64
#define NBLK   224
#define FPAD   8      // ints between flags (32B)

#define RS_B 6144     // LDS row stride bytes, B-role aggT: 3072 bf16
#define KT_OFF 131072 // LDS byte offset of kt slab in A-role

#define MFMA16(a,b,c) __builtin_amdgcn_mfma_f32_16x16x32_bf16((a),(b),(c),0,0,0)

// ---------------------------------------------------------------------------
__global__ __launch_bounds__(256) void k_xconv(const float* __restrict__ in,
                                               bf16* __restrict__ o, int n4) {
    const int i = blockIdx.x * 256 + threadIdx.x;
    if (i < n4) {
        const float4 v = ((const float4*)in)[i];
        bf16 tmp[4] = {__float2bfloat16(v.x), __float2bfloat16(v.y),
                       __float2bfloat16(v.z), __float2bfloat16(v.w)};
        ((uint2*)o)[i] = *(const uint2*)tmp;
    }
}

// ---------------------------------------------------------------------------
__global__ __launch_bounds__(256) void k_transpose(const float* __restrict__ in,
                                                   bf16* __restrict__ out,
                                                   int C, int out_stride, int out_off) {
    __shared__ bf16 tile[64][65];
    const int tc = blockIdx.x * 64, tr = blockIdx.y * 64;
    const int tx = threadIdx.x & 63, ty0 = threadIdx.x >> 6;
#pragma unroll
    for (int i = 0; i < 64; i += 4)
        tile[ty0 + i][tx] = __float2bfloat16(in[(tr + ty0 + i) * C + tc + tx]);
    __syncthreads();
#pragma unroll
    for (int i = 0; i < 64; i += 4)
        out[(tc + ty0 + i) * out_stride + out_off + tr + tx] = tile[tx][ty0 + i];
}

// ---------------------------------------------------------------------------
struct AttPtrs { const float* p[12]; };

__global__ __launch_bounds__(256) void k_scal(AttPtrs ap, float* __restrict__ scal) {
    __shared__ float red[256];
    const int tid = threadIdx.x;
    for (int q = 0; q < 6; ++q) {
        const float* l = ap.p[2 * q];
        const float* r = ap.p[2 * q + 1];
        float s = 0.f;
        for (int i = tid; i < 1024; i += 256)
            s += l[i] * r[i];
        red[tid] = s; __syncthreads();
        for (int o = 128; o > 0; o >>= 1) {
            if (tid < o) red[tid] += red[tid + o];
            __syncthreads();
        }
        if (tid == 0) scal[q] = red[0];
        __syncthreads();
    }
}

// ---------------------------------------------------------------------------
// block collectives (256 threads = 4 waves)
__device__ __forceinline__ float wave_sum(float v) {
#pragma unroll
    for (int o = 32; o > 0; o >>= 1) v += __shfl_xor(v, o, 64);
    return v;
}
__device__ __forceinline__ float wave_max(float v) {
#pragma unroll
    for (int o = 32; o > 0; o >>= 1) v = fmaxf(v, __shfl_xor(v, o, 64));
    return v;
}
__device__ __forceinline__ float wave_scan(float v, int lane) {
#pragma unroll
    for (int o = 1; o < 64; o <<= 1) {
        float n = __shfl_up(v, o, 64);
        if (lane >= o) v += n;
    }
    return v;
}
__device__ __forceinline__ float block_sum(float v, float* sm4, int w, int lane) {
    float s = wave_sum(v);
    if (lane == 0) sm4[w] = s;
    __syncthreads();
    float r = sm4[0] + sm4[1] + sm4[2] + sm4[3];
    __syncthreads();
    return r;
}
__device__ __forceinline__ float block_max(float v, float* sm4, int w, int lane) {
    float s = wave_max(v);
    if (lane == 0) sm4[w] = s;
    __syncthreads();
    float r = fmaxf(fmaxf(sm4[0], sm4[1]), fmaxf(sm4[2], sm4[3]));
    __syncthreads();
    return r;
}
__device__ __forceinline__ float block_scan(float v, float* sm4, int w, int lane, float* total) {
    float ws = wave_scan(v, lane);
    if (lane == 63) sm4[w] = ws;
    __syncthreads();
    float base = 0.f;
    if (w > 0) base += sm4[0];
    if (w > 1) base += sm4[1];
    if (w > 2) base += sm4[2];
    *total = sm4[0] + sm4[1] + sm4[2] + sm4[3];
    __syncthreads();
    return base + ws;
}
__device__ __forceinline__ float sigm(float x) { return 1.f / (1.f + __expf(-x)); }

// ---------------------------------------------------------------------------
// sc1 (coherence-point) data path: relaxed agent-scope atomics.
__device__ __forceinline__ u64 ald64(const void* p) {
    return __hip_atomic_load((const u64*)p, __ATOMIC_RELAXED, __HIP_MEMORY_SCOPE_AGENT);
}
__device__ __forceinline__ bf16x8 ald16B(const bf16* p) {
    union { bf16x8 v; u64 u[2]; } r;
    r.u[0] = ald64(p);
    r.u[1] = ald64((const char*)p + 8);
    return r.v;
}
__device__ __forceinline__ f32x4 ald_f4(const float* p) {
    union { f32x4 v; u64 u[2]; } r;
    r.u[0] = ald64(p);
    r.u[1] = ald64(p + 2);
    return r.v;
}
__device__ __forceinline__ float ald_f(const float* p) {
    return __hip_atomic_load(p, __ATOMIC_RELAXED, __HIP_MEMORY_SCOPE_AGENT);
}
__device__ __forceinline__ void ast64(void* p, u64 v) {
    __hip_atomic_store((u64*)p, v, __ATOMIC_RELAXED, __HIP_MEMORY_SCOPE_AGENT);
}
__device__ __forceinline__ void ast32(void* p, unsigned v) {
    __hip_atomic_store((unsigned*)p, v, __ATOMIC_RELAXED, __HIP_MEMORY_SCOPE_AGENT);
}
__device__ __forceinline__ unsigned bfbits(bf16 h) {
    unsigned short s; __builtin_memcpy(&s, &h, 2); return (unsigned)s;
}
__device__ __forceinline__ u64 packf2(float a, float b) {
    union { float f[2]; u64 u; } r; r.f[0] = a; r.f[1] = b; return r.u;
}

// flag barriers, fence-free (see v3 comment)
__device__ __forceinline__ void signal_flag(int* f, int v) {
    __syncthreads();
    if (threadIdx.x == 0)
        __hip_atomic_store(f, v, __ATOMIC_RELAXED, __HIP_MEMORY_SCOPE_AGENT);
}
__device__ __forceinline__ void wait_ge(const int* f, int n, int tgt) {
    if (threadIdx.x < 64) {
        for (;;) {
            int mn = 0x7fffffff;
            for (int i = threadIdx.x; i < n; i += 64) {
                const int v = __hip_atomic_load(f + i * FPAD, __ATOMIC_RELAXED,
                                                __HIP_MEMORY_SCOPE_AGENT);
                mn = v < mn ? v : mn;
            }
            if (__all(mn >= tgt)) break;
            __builtin_amdgcn_s_sleep(1);
        }
    }
    __syncthreads();
}

// swizzled LDS read
__device__ __forceinline__ bf16x8 lds_rd(const char* s, int nloc, int kb, int rs) {
    return *(const bf16x8*)(s + nloc * rs + (kb ^ ((nloc & 7) << 4)));
}

// ---------------------------------------------------------------------------
__global__ __launch_bounds__(256, 1) void k_persist(
    const bf16* __restrict__ xbf, const bf16* __restrict__ kt,
    const bf16* __restrict__ wrct, const bf16* __restrict__ aggt,
    float* __restrict__ zp, bf16* __restrict__ abuf,
    float* __restrict__ c32, bf16* __restrict__ obuf,
    const float* __restrict__ scal, const float* __restrict__ bias,
    float* __restrict__ out, int* __restrict__ ctr)
{
    __shared__ __align__(16) char smem[147456];   // A: 128KB weights + 16KB kt
    __shared__ float sm4[4];

    const int bid = blockIdx.x, tid = threadIdx.x;
    const int w = tid >> 6, lane = tid & 63;
    const int ml = lane & 15, q = lane >> 4;
    int* fA = ctr;            // [160*FPAD] z-partials ready (value t+1)
    int* fB = ctr + 1280;     // [64*FPAD]  O rows ready
    int* fC = ctr + 1792;     // [64*FPAD]  h,c state ready

    if (bid < NBLK_A) {
        // =================== role A: z-GEMM partial ====================
        // wave = 16-row group (rows w*16..w*16+15) x ALL 128 cols -> A-frag
        // loads are duplication-free across waves.
        const int cg = bid >> 2;            // col group: cols cg*128..+127
        const int kq = bid & 3;             // K quarter: 0,1=h halves; 2,3=c halves
        const int n0 = cg * 128;
        const int kwbase = (kq < 2) ? kq * 512 : 1024 + (kq - 2) * 512;
        const int kA0 = (kq & 1) * 512;     // offset within h (or c) plane

        // stage weights [128 cols][512 k] bf16, swizzled, rs=1024B
        for (int i = 0; i < 32; ++i) {
            const int cid = i * 256 + tid;
            const int row = cid >> 6, k = (cid & 63) * 8;
            bf16x8 v = *(const bf16x8*)(wrct + (size_t)(n0 + row) * K2 + kwbase + k);
            *(bf16x8*)(smem + row * 1024 + ((k * 2) ^ ((row & 7) << 4))) = v;
        }
        // stage kt slab [128 cols][64 k] bf16, swizzled, rs=128B
        for (int i = 0; i < 4; ++i) {
            const int cid = i * 256 + tid;
            const int row = cid >> 3, k = (cid & 7) * 8;
            bf16x8 v = *(const bf16x8*)(kt + (size_t)(n0 + row) * DIM + kq * 64 + k);
            *(bf16x8*)(smem + KT_OFF + row * 128 + ((k * 2) ^ ((row & 7) << 4))) = v;
        }
        __syncthreads();

        const int arow = w * 16 + ml;       // this lane's batch row (A-frag row)
        const bf16* hiP = abuf + (kq < 2 ? 0 : 2) * 65536 + arow * U + kA0;
        const bf16* loP = abuf + (kq < 2 ? 1 : 3) * 65536 + arow * U + kA0;
        const bf16* xrow = xbf + (size_t)arow * TSTEPS * DIM;
        float* zpq = zp + (size_t)kq * 64 * N5;

        // per k-group of 64: hi/lo, 2 half-chunks of 32 each (8 u64 loads)
#define LOADG(G, B) do { \
            const int b_ = (G) * 64 + q * 8; \
            h0[B] = ald16B(hiP + b_);        h1[B] = ald16B(hiP + b_ + 32); \
            l0[B] = ald16B(loP + b_);        l1[B] = ald16B(loP + b_ + 32); \
        } while (0)

        for (int t = 0; t < TSTEPS; ++t) {
            f32x4 acc[8];
#pragma unroll
            for (int i = 0; i < 8; ++i) acc[i] = (f32x4){0.f, 0.f, 0.f, 0.f};

            // ---- x @ kernel slice (64 k): independent of state, before wait
#pragma unroll
            for (int cx = 0; cx < 2; ++cx) {
                const bf16x8 ax = *(const bf16x8*)(xrow + t * DIM + kq * 64 + cx * 32 + q * 8);
#pragma unroll
                for (int ct = 0; ct < 8; ++ct) {
                    const bf16x8 b = lds_rd(smem + KT_OFF, ct * 16 + ml, cx * 64 + q * 16, 128);
                    acc[ct] = MFMA16(ax, b, acc[ct]);
                }
            }

            wait_ge(fC, NBLK_B, t);          // state of step t-1 ready

            // ---- (h|c) quarter, hi+lo: 8 k-groups of 64, 4-deep ring,
            //      distance-3 prefetch (load (g+3)&3, consume g&3 — disjoint)
            {
                bf16x8 h0[4], h1[4], l0[4], l1[4];
                LOADG(0, 0);
                LOADG(1, 1);
                LOADG(2, 2);
#pragma unroll
                for (int g = 0; g < 8; ++g) {
                    if (g < 5) LOADG(g + 3, (g + 3) & 3);
                    const int B_ = g & 3;
#pragma unroll
                    for (int c = 0; c < 2; ++c) {
                        const bf16x8 ah = c ? h1[B_] : h0[B_];
                        const bf16x8 al = c ? l1[B_] : l0[B_];
#pragma unroll
                        for (int ct = 0; ct < 8; ++ct) {
                            const bf16x8 b = lds_rd(smem, ct * 16 + ml,
                                                    g * 128 + c * 64 + q * 16, 1024);
                            acc[ct] = MFMA16(ah, b, acc[ct]);
                            acc[ct] = MFMA16(al, b, acc[ct]);
                        }
                    }
                }
            }

            // ---- epilogue: z partials, lane-pair packed u64 sc1 stores
#pragma unroll
            for (int ct = 0; ct < 8; ++ct)
#pragma unroll
                for (int r = 0; r < 4; ++r) {
                    const float v = acc[ct][r];
                    const float pv = __shfl_xor(v, 1, 64);
                    if (!(ml & 1)) {
                        const int row = w * 16 + q * 4 + r;
                        const int col = n0 + ct * 16 + ml;
                        ast64(&zpq[row * N5 + col], packf2(v, pv));
                    }
                }
            signal_flag(fA + bid * FPAD, t + 1);
        }
#undef LOADG
    } else {
        // ========= role B: gates (row rb) + agg-GEMM (16 u-cols) + state =========
        const int rb = bid - NBLK_A;
        const int n0b = rb * 16;
        // stage aggT tile [16][3072] bf16, swizzled, rs=6144B
        for (int i = 0; i < 24; ++i) {
            const int cid = i * 256 + tid;
            const int nloc = cid / 384, kc = cid - nloc * 384;
            const int k = kc * 8;
            bf16x8 v = *(const bf16x8*)(aggt + (size_t)(n0b + nloc) * 3072 + k);
            *(bf16x8*)(smem + nloc * RS_B + ((k * 2) ^ ((nloc & 7) << 4))) = v;
        }
        __syncthreads();

        const float s_ud = scal[0], s_ur = scal[1], s_ru = scal[2],
                    s_rd = scal[3], s_du = scal[4], s_dr = scal[5];
        const int rowA = w * 16 + ml;
        const bf16* orow = obuf + rowA * 3072;
        float* cpriv = c32 + rb * 1024;      // block-private [64 rows][16]

#define LOADO(G, BUF) do { _Pragma("unroll") \
        for (int j_ = 0; j_ < 8; ++j_) \
            ob[BUF][j_] = ald16B(orow + ((G) * 8 + j_) * 32 + q * 8); \
        } while (0)

        for (int t = 0; t < TSTEPS; ++t) {
            wait_ge(fA, NBLK_A, t + 1);      // all z partials of step t ready
            // ---------------- P2: gates for batch row rb ----------------
            {
                f32x4 zu = {0.f,0.f,0.f,0.f}, zd = {0.f,0.f,0.f,0.f}, zn = {0.f,0.f,0.f,0.f};
#pragma unroll
                for (int kqi = 0; kqi < 4; ++kqi) {
                    const float* bp = zp + (size_t)kqi * 64 * N5 + rb * N5;
                    zu += ald_f4(bp + tid * 4);
                    zd += ald_f4(bp + U + tid * 4);
                    zn += ald_f4(bp + 2 * U + tid * 4);
                }
                zu += ((const f32x4*)bias)[tid];
                zd += ((const f32x4*)(bias + U))[tid];
                zn += ((const f32x4*)(bias + 2 * U))[tid];

                float mup = block_max(fmaxf(fmaxf(zu[0], zu[1]), fmaxf(zu[2], zu[3])), sm4, w, lane);
                const float e0 = __expf(zu[0] - mup), e1 = __expf(zu[1] - mup),
                            e2 = __expf(zu[2] - mup), e3 = __expf(zu[3] - mup);
                float totu;
                float inclu = block_scan(e0 + e1 + e2 + e3, sm4, w, lane, &totu);
                const float exclu = inclu - (e0 + e1 + e2 + e3);
                const float inv_u = 1.f / totu;
                const float u0 = (exclu + e0) * inv_u;
                const float u1 = (exclu + e0 + e1) * inv_u;
                const float u2 = (exclu + e0 + e1 + e2) * inv_u;
                const float u3 = (exclu + e0 + e1 + e2 + e3) * inv_u;

                float mdn = block_max(fmaxf(fmaxf(zd[0], zd[1]), fmaxf(zd[2], zd[3])), sm4, w, lane);
                const float f0 = __expf(zd[0] - mdn), f1 = __expf(zd[1] - mdn),
                            f2 = __expf(zd[2] - mdn), f3 = __expf(zd[3] - mdn);
                float totd;
                float incld = block_scan(f0 + f1 + f2 + f3, sm4, w, lane, &totd);
                const float excld = incld - (f0 + f1 + f2 + f3);
                const float inv_d = 1.f / totd;
                const float d0 = (totd - excld) * inv_d;
                const float d1 = (totd - excld - f0) * inv_d;
                const float d2 = (totd - excld - f0 - f1) * inv_d;
                const float d3 = (totd - excld - f0 - f1 - f2) * inv_d;

                const float du = block_sum(d0 * u0 + d1 * u1 + d2 * u2 + d3 * u3, sm4, w, lane);
                const float ru = block_sum(zn[0] * u0 + zn[1] * u1 + zn[2] * u2 + zn[3] * u3, sm4, w, lane);
                const float dr = block_sum(d0 * zn[0] + d1 * zn[1] + d2 * zn[2] + d3 * zn[3], sm4, w, lane);

                bf16* orw = obuf + rb * 3072;
                const int j0 = tid * 4;
                const float uu[4] = {u0, u1, u2, u3};
                const float dd[4] = {d0, d1, d2, d3};
                const float rr[4] = {zn[0], zn[1], zn[2], zn[3]};
                union { bf16 h[4]; u64 u; } p1, p2, p3;
#pragma unroll
                for (int i = 0; i < 4; ++i) {
                    p1.h[i] = __float2bfloat16(sigm(s_ud * uu[i] * du) + sigm(s_ur * uu[i] * ru));
                    p2.h[i] = __float2bfloat16(sigm(s_ru * rr[i] * ru) + sigm(s_rd * rr[i] * dr));
                    p3.h[i] = __float2bfloat16(sigm(s_du * dd[i] * du) + sigm(s_dr * dd[i] * dr));
                }
                ast64(orw + j0,         p1.u);
                ast64(orw + U + j0,     p2.u);
                ast64(orw + 2 * U + j0, p3.u);
            }
            signal_flag(fB + rb * FPAD, t + 1);

            // hoisted z3/z4 (depends only on fA): loads fly during fB wait
            float z3v[4], z4v[4];
            {
                const int col = n0b + ml;
                const int r0 = w * 16 + q * 4;
#pragma unroll
                for (int r = 0; r < 4; ++r) {
                    z3v[r] = bias[3 * U + col];
                    z4v[r] = bias[4 * U + col];
#pragma unroll
                    for (int kqi = 0; kqi < 4; ++kqi) {
                        const float* zr = zp + (size_t)kqi * 64 * N5 + (size_t)(r0 + r) * N5;
                        z3v[r] += ald_f(zr + 3 * U + col);
                        z4v[r] += ald_f(zr + 4 * U + col);
                    }
                }
            }
            wait_ge(fB, NBLK_B, t + 1);      // all O rows ready
            // -------- P3: f = sigm(O@agg); state update; emit out --------
            {
                f32x4 p0 = {0.f, 0.f, 0.f, 0.f}, p1 = {0.f, 0.f, 0.f, 0.f};
                bf16x8 ob[4][8];
                LOADO(0, 0);
                LOADO(1, 1);
                LOADO(2, 2);
#pragma unroll
                for (int g = 0; g < 12; ++g) {
                    if (g < 9) LOADO(g + 3, (g + 3) & 3);
#pragma unroll
                    for (int j = 0; j < 8; ++j) {
                        const int ch = g * 8 + j;
                        const int kb = ch * 64 + q * 16;
                        const bf16x8 b = lds_rd(smem, ml, kb, RS_B);
                        if (j & 1) p1 = MFMA16(ob[g & 3][j], b, p1);
                        else       p0 = MFMA16(ob[g & 3][j], b, p0);
                    }
                }
                const f32x4 accv = p0 + p1;
                const int col = n0b + ml;
                const int r0 = w * 16 + q * 4;
#pragma unroll
                for (int r = 0; r < 4; ++r) {
                    const int row = r0 + r;
                    const float f = sigm(accv[r]);
                    const float cold = cpriv[row * 16 + ml];
                    const float cn = f * cold + (1.f - f) * tanhf(z4v[r]);
                    const float hn = z3v[r] * tanhf(cn);
                    cpriv[row * 16 + ml] = cn;
                    const bf16 chb = __float2bfloat16(cn);
                    const bf16 clb = __float2bfloat16(cn - __bfloat162float(chb));
                    const bf16 hhb = __float2bfloat16(hn);
                    const bf16 hlb = __float2bfloat16(hn - __bfloat162float(hhb));
                    // pack lane-pairs (cols col,col+1) into 32-bit sc1 stores
                    unsigned vh = bfbits(hhb), vl = bfbits(hlb),
                             vc = bfbits(chb), vx = bfbits(clb);
                    const unsigned ph = (unsigned)__shfl_xor((int)vh, 1, 64);
                    const unsigned pl = (unsigned)__shfl_xor((int)vl, 1, 64);
                    const unsigned pc = (unsigned)__shfl_xor((int)vc, 1, 64);
                    const unsigned px = (unsigned)__shfl_xor((int)vx, 1, 64);
                    if (!(ml & 1)) {
                        const int eo = row * U + col;
                        ast32((unsigned*)(abuf + 0 * 65536 + eo), vh | (ph << 16));
                        ast32((unsigned*)(abuf + 1 * 65536 + eo), vl | (pl << 16));
                        ast32((unsigned*)(abuf + 2 * 65536 + eo), vc | (pc << 16));
                        ast32((unsigned*)(abuf + 3 * 65536 + eo), vx | (px << 16));
                    }
                    out[((size_t)row * TSTEPS + t) * U + col] = hn;
                }
            }
            signal_flag(fC + rb * FPAD, t + 1);
        }
#undef LOADO
    }
}

// ---------------------------------------------------------------------------
extern "C" void kernel_launch(void* const* d_in, const int* in_sizes, int n_in,
                              void* d_out, int out_size, void* d_ws, size_t ws_size,
                              hipStream_t stream) {
    (void)in_sizes; (void)n_in; (void)out_size; (void)ws_size;
    const float* x    = (const float*)d_in[0];
    const float* Wk   = (const float*)d_in[1];   // (256,5120)
    const float* Wr   = (const float*)d_in[2];   // (1024,5120)
    const float* Wc   = (const float*)d_in[3];   // (1024,5120)
    const float* bias = (const float*)d_in[4];   // (5120)
    const float* agg  = (const float*)d_in[5];   // (3072,1024)

    char* ws = (char*)d_ws;
    bf16*  wrct = (bf16*)(ws + OFF_WRC);
    bf16*  kt   = (bf16*)(ws + OFF_KT);
    bf16*  aggt = (bf16*)(ws + OFF_AGGT);
    bf16*  xbf  = (bf16*)(ws + OFF_XBF);
    float* zp   = (float*)(ws + OFF_ZP);
    bf16*  abuf = (bf16*)(ws + OFF_ABUF);
    float* c32  = (float*)(ws + OFF_C32);
    bf16*  obuf = (bf16*)(ws + OFF_OBUF);
    float* scal = (float*)(ws + OFF_SCAL);
    int*   ctr  = (int*)(ws + OFF_CTR);
    float* out  = (float*)d_out;

    hipMemsetAsync(abuf, 0, 4 * 65536 * sizeof(bf16), stream);
    hipMemsetAsync(c32, 0, BATCH * U * sizeof(float), stream);
    hipMemsetAsync(ctr, 0, 12288, stream);   // flag zone reset each launch

    // one-time conversions / transposes
    k_xconv<<<(BATCH * TSTEPS * DIM / 4 + 255) / 256, 256, 0, stream>>>(x, xbf, BATCH * TSTEPS * DIM / 4);
    k_transpose<<<dim3(5120 / 64, 1024 / 64), 256, 0, stream>>>(Wr, wrct, 5120, 2048, 0);
    k_transpose<<<dim3(5120 / 64, 1024 / 64), 256, 0, stream>>>(Wc, wrct, 5120, 2048, 1024);
    k_transpose<<<dim3(5120 / 64, 256 / 64),  256, 0, stream>>>(Wk, kt,   5120, 256, 0);
    k_transpose<<<dim3(1024 / 64, 3072 / 64), 256, 0, stream>>>(agg, aggt, 1024, 3072, 0);

    AttPtrs ap;
    for (int i = 0; i < 12; ++i) ap.p[i] = (const float*)d_in[6 + i];
    k_scal<<<1, 256, 0, stream>>>(ap, scal);

    // the whole recurrence: one persistent launch
    k_persist<<<NBLK, 256, 0, stream>>>(xbf, kt, wrct, aggt, zp, abuf, c32,
                                        obuf, scal, bias, out, ctr);
}

// Round 6
// 3855.372 us; speedup vs baseline: 2.3638x; 1.7061x over previous
//
#include <hip/hip_runtime.h>
#include <hip/hip_bf16.h>

// ---------------------------------------------------------------------------
// MA_LSTM on MI355X (gfx950) — persistent kernel, v6: O-gather k-split.
// v5 post-mortem: serial coherent-traffic chain ~55MB/step @ ~3.2TB/s + hops
// = ~51us/step. Biggest item: agg-GEMM O-gather (64 blocks x full 384KB O =
// 24.6MB/step, 64x duplication). v6: B-blocks = 16 col-groups x 4 K-quarters;
// aggT LDS slice 64cols x 768k (same 96KB); each block reads only its 768-k
// O slice (96KB) -> 6.1MB/step. Partial-f exchange via pbuf (in the dead kt
// region) + sibling flags. fA wait split (P2: flags 0..95; z3/z4: 96..159
// polled late, loads overlap MFMA).
//   blocks 0..159 ("A"): z-GEMM partials (40 col-groups x 4 K-quarters).
//   blocks 160..223 ("B"): gates (row rb) + agg-GEMM partial (64 cols x 768k)
//                          + partial exchange + state update (16 cols).
// Fence-free: cross-block data via relaxed AGENT-scope atomics (sc1).
// ---------------------------------------------------------------------------

typedef short  bf16x8 __attribute__((ext_vector_type(8)));
typedef float  f32x4  __attribute__((ext_vector_type(4)));
typedef __hip_bfloat16 bf16;
typedef unsigned long long u64;

#define U 1024
#define BATCH 64
#define TSTEPS 128
#define DIM 256
#define N5 5120
#define K2 2048   // h(1024) + c(1024)

// ---- workspace layout (bytes) ----
#define OFF_WRC   0u                       // bf16 [5120][2048]  (Wr^T | Wc^T)
#define OFF_KT    20971520u                // bf16 [5120][256]   kernel^T (staging only)
#define OFF_AGGT  23592960u                // bf16 [1024][3072]  aggregation^T
#define OFF_XBF   29884416u                // bf16 [64][128][256] x in bf16
#define OFF_ZP    34078720u                // f32  [4][64][5120] z partials
#define OFF_ABUF  39321600u                // bf16 [4][64][1024] h_hi,h_lo,c_hi,c_lo
#define OFF_C32   39845888u                // f32  c state (block-private stripes)
#define OFF_OBUF  40108032u                // bf16 [64][3072]
#define OFF_SCAL  40501248u                // f32  [8]
#define OFF_CTR   40501504u                // int flags (12KB zone, 32B-padded)
#define OFF_PB    OFF_KT                   // f32 [64][64][64] f-partials (kt dead after staging)

#define NBLK_A 160
#define NBLK_B 64
#define NBLK   224
#define FPAD   8      // ints between flags (32B)

#define KT_OFF 131072 // LDS byte offset of kt slab in A-role

#define MFMA16(a,b,c) __builtin_amdgcn_mfma_f32_16x16x32_bf16((a),(b),(c),0,0,0)

// ---------------------------------------------------------------------------
__global__ __launch_bounds__(256) void k_xconv(const float* __restrict__ in,
                                               bf16* __restrict__ o, int n4) {
    const int i = blockIdx.x * 256 + threadIdx.x;
    if (i < n4) {
        const float4 v = ((const float4*)in)[i];
        bf16 tmp[4] = {__float2bfloat16(v.x), __float2bfloat16(v.y),
                       __float2bfloat16(v.z), __float2bfloat16(v.w)};
        ((uint2*)o)[i] = *(const uint2*)tmp;
    }
}

// ---------------------------------------------------------------------------
__global__ __launch_bounds__(256) void k_transpose(const float* __restrict__ in,
                                                   bf16* __restrict__ out,
                                                   int C, int out_stride, int out_off) {
    __shared__ bf16 tile[64][65];
    const int tc = blockIdx.x * 64, tr = blockIdx.y * 64;
    const int tx = threadIdx.x & 63, ty0 = threadIdx.x >> 6;
#pragma unroll
    for (int i = 0; i < 64; i += 4)
        tile[ty0 + i][tx] = __float2bfloat16(in[(tr + ty0 + i) * C + tc + tx]);
    __syncthreads();
#pragma unroll
    for (int i = 0; i < 64; i += 4)
        out[(tc + ty0 + i) * out_stride + out_off + tr + tx] = tile[tx][ty0 + i];
}

// ---------------------------------------------------------------------------
struct AttPtrs { const float* p[12]; };

__global__ __launch_bounds__(256) void k_scal(AttPtrs ap, float* __restrict__ scal) {
    __shared__ float red[256];
    const int tid = threadIdx.x;
    for (int q = 0; q < 6; ++q) {
        const float* l = ap.p[2 * q];
        const float* r = ap.p[2 * q + 1];
        float s = 0.f;
        for (int i = tid; i < 1024; i += 256)
            s += l[i] * r[i];
        red[tid] = s; __syncthreads();
        for (int o = 128; o > 0; o >>= 1) {
            if (tid < o) red[tid] += red[tid + o];
            __syncthreads();
        }
        if (tid == 0) scal[q] = red[0];
        __syncthreads();
    }
}

// ---------------------------------------------------------------------------
// block collectives (256 threads = 4 waves)
__device__ __forceinline__ float wave_sum(float v) {
#pragma unroll
    for (int o = 32; o > 0; o >>= 1) v += __shfl_xor(v, o, 64);
    return v;
}
__device__ __forceinline__ float wave_max(float v) {
#pragma unroll
    for (int o = 32; o > 0; o >>= 1) v = fmaxf(v, __shfl_xor(v, o, 64));
    return v;
}
__device__ __forceinline__ float wave_scan(float v, int lane) {
#pragma unroll
    for (int o = 1; o < 64; o <<= 1) {
        float n = __shfl_up(v, o, 64);
        if (lane >= o) v += n;
    }
    return v;
}
__device__ __forceinline__ float block_sum(float v, float* sm4, int w, int lane) {
    float s = wave_sum(v);
    if (lane == 0) sm4[w] = s;
    __syncthreads();
    float r = sm4[0] + sm4[1] + sm4[2] + sm4[3];
    __syncthreads();
    return r;
}
__device__ __forceinline__ float block_max(float v, float* sm4, int w, int lane) {
    float s = wave_max(v);
    if (lane == 0) sm4[w] = s;
    __syncthreads();
    float r = fmaxf(fmaxf(sm4[0], sm4[1]), fmaxf(sm4[2], sm4[3]));
    __syncthreads();
    return r;
}
__device__ __forceinline__ float block_scan(float v, float* sm4, int w, int lane, float* total) {
    float ws = wave_scan(v, lane);
    if (lane == 63) sm4[w] = ws;
    __syncthreads();
    float base = 0.f;
    if (w > 0) base += sm4[0];
    if (w > 1) base += sm4[1];
    if (w > 2) base += sm4[2];
    *total = sm4[0] + sm4[1] + sm4[2] + sm4[3];
    __syncthreads();
    return base + ws;
}
__device__ __forceinline__ float sigm(float x) { return 1.f / (1.f + __expf(-x)); }

// ---------------------------------------------------------------------------
// sc1 (coherence-point) data path: relaxed agent-scope atomics.
__device__ __forceinline__ u64 ald64(const void* p) {
    return __hip_atomic_load((const u64*)p, __ATOMIC_RELAXED, __HIP_MEMORY_SCOPE_AGENT);
}
__device__ __forceinline__ bf16x8 ald16B(const bf16* p) {
    union { bf16x8 v; u64 u[2]; } r;
    r.u[0] = ald64(p);
    r.u[1] = ald64((const char*)p + 8);
    return r.v;
}
__device__ __forceinline__ f32x4 ald_f4(const float* p) {
    union { f32x4 v; u64 u[2]; } r;
    r.u[0] = ald64(p);
    r.u[1] = ald64(p + 2);
    return r.v;
}
__device__ __forceinline__ float ald_f(const float* p) {
    return __hip_atomic_load(p, __ATOMIC_RELAXED, __HIP_MEMORY_SCOPE_AGENT);
}
__device__ __forceinline__ void ast64(void* p, u64 v) {
    __hip_atomic_store((u64*)p, v, __ATOMIC_RELAXED, __HIP_MEMORY_SCOPE_AGENT);
}
__device__ __forceinline__ void ast32(void* p, unsigned v) {
    __hip_atomic_store((unsigned*)p, v, __ATOMIC_RELAXED, __HIP_MEMORY_SCOPE_AGENT);
}
__device__ __forceinline__ unsigned bfbits(bf16 h) {
    unsigned short s; __builtin_memcpy(&s, &h, 2); return (unsigned)s;
}
__device__ __forceinline__ u64 packf2(float a, float b) {
    union { float f[2]; u64 u; } r; r.f[0] = a; r.f[1] = b; return r.u;
}

// flag barriers, fence-free (see v3 comment)
__device__ __forceinline__ void signal_flag(int* f, int v) {
    __syncthreads();
    if (threadIdx.x == 0)
        __hip_atomic_store(f, v, __ATOMIC_RELAXED, __HIP_MEMORY_SCOPE_AGENT);
}
__device__ __forceinline__ void wait_ge(const int* f, int n, int tgt) {
    if (threadIdx.x < 64) {
        for (;;) {
            int mn = 0x7fffffff;
            for (int i = threadIdx.x; i < n; i += 64) {
                const int v = __hip_atomic_load(f + i * FPAD, __ATOMIC_RELAXED,
                                                __HIP_MEMORY_SCOPE_AGENT);
                mn = v < mn ? v : mn;
            }
            if (__all(mn >= tgt)) break;
            __builtin_amdgcn_s_sleep(1);
        }
    }
    __syncthreads();
}

// swizzled LDS read
__device__ __forceinline__ bf16x8 lds_rd(const char* s, int nloc, int kb, int rs) {
    return *(const bf16x8*)(s + nloc * rs + (kb ^ ((nloc & 7) << 4)));
}

// ---------------------------------------------------------------------------
__global__ __launch_bounds__(256, 1) void k_persist(
    const bf16* __restrict__ xbf, const bf16* __restrict__ kt,
    const bf16* __restrict__ wrct, const bf16* __restrict__ aggt,
    float* __restrict__ zp, bf16* __restrict__ abuf,
    float* __restrict__ c32, bf16* __restrict__ obuf,
    float* __restrict__ pbuf,
    const float* __restrict__ scal, const float* __restrict__ bias,
    float* __restrict__ out, int* __restrict__ ctr)
{
    __shared__ __align__(16) char smem[147456];   // A: 128KB weights + 16KB kt; B: 96KB aggT slice
    __shared__ float sm4[4];

    const int bid = blockIdx.x, tid = threadIdx.x;
    const int w = tid >> 6, lane = tid & 63;
    const int ml = lane & 15, q = lane >> 4;
    int* fA = ctr;            // [160*FPAD] z-partials ready (value t+1)
    int* fB = ctr + 1280;     // [64*FPAD]  O rows ready
    int* fC = ctr + 1792;     // [64*FPAD]  h,c state ready
    int* fP = ctr + 2304;     // [64*FPAD]  f-partials ready

    if (bid < NBLK_A) {
        // =================== role A: z-GEMM partial ====================
        const int cg = bid >> 2;            // col group: cols cg*128..+127
        const int kq = bid & 3;             // K quarter: 0,1=h halves; 2,3=c halves
        const int n0 = cg * 128;
        const int kwbase = (kq < 2) ? kq * 512 : 1024 + (kq - 2) * 512;
        const int kA0 = (kq & 1) * 512;     // offset within h (or c) plane

        // stage weights [128 cols][512 k] bf16, swizzled, rs=1024B
        for (int i = 0; i < 32; ++i) {
            const int cid = i * 256 + tid;
            const int row = cid >> 6, k = (cid & 63) * 8;
            bf16x8 v = *(const bf16x8*)(wrct + (size_t)(n0 + row) * K2 + kwbase + k);
            *(bf16x8*)(smem + row * 1024 + ((k * 2) ^ ((row & 7) << 4))) = v;
        }
        // stage kt slab [128 cols][64 k] bf16, swizzled, rs=128B
        for (int i = 0; i < 4; ++i) {
            const int cid = i * 256 + tid;
            const int row = cid >> 3, k = (cid & 7) * 8;
            bf16x8 v = *(const bf16x8*)(kt + (size_t)(n0 + row) * DIM + kq * 64 + k);
            *(bf16x8*)(smem + KT_OFF + row * 128 + ((k * 2) ^ ((row & 7) << 4))) = v;
        }
        __syncthreads();

        const int arow = w * 16 + ml;       // this lane's batch row (A-frag row)
        const bf16* hiP = abuf + (kq < 2 ? 0 : 2) * 65536 + arow * U + kA0;
        const bf16* loP = abuf + (kq < 2 ? 1 : 3) * 65536 + arow * U + kA0;
        const bf16* xrow = xbf + (size_t)arow * TSTEPS * DIM;
        float* zpq = zp + (size_t)kq * 64 * N5;

#define LOADG(G, B) do { \
            const int b_ = (G) * 64 + q * 8; \
            h0[B] = ald16B(hiP + b_);        h1[B] = ald16B(hiP + b_ + 32); \
            l0[B] = ald16B(loP + b_);        l1[B] = ald16B(loP + b_ + 32); \
        } while (0)

        for (int t = 0; t < TSTEPS; ++t) {
            f32x4 acc[8];
#pragma unroll
            for (int i = 0; i < 8; ++i) acc[i] = (f32x4){0.f, 0.f, 0.f, 0.f};

            // ---- x @ kernel slice (64 k): independent of state, before wait
#pragma unroll
            for (int cx = 0; cx < 2; ++cx) {
                const bf16x8 ax = *(const bf16x8*)(xrow + t * DIM + kq * 64 + cx * 32 + q * 8);
#pragma unroll
                for (int ct = 0; ct < 8; ++ct) {
                    const bf16x8 b = lds_rd(smem + KT_OFF, ct * 16 + ml, cx * 64 + q * 16, 128);
                    acc[ct] = MFMA16(ax, b, acc[ct]);
                }
            }

            wait_ge(fC, NBLK_B, t);          // state of step t-1 ready

            // ---- (h|c) quarter, hi+lo: 8 k-groups of 64, 4-deep ring,
            //      distance-3 prefetch (load (g+3)&3, consume g&3 — disjoint)
            {
                bf16x8 h0[4], h1[4], l0[4], l1[4];
                LOADG(0, 0);
                LOADG(1, 1);
                LOADG(2, 2);
#pragma unroll
                for (int g = 0; g < 8; ++g) {
                    if (g < 5) LOADG(g + 3, (g + 3) & 3);
                    const int B_ = g & 3;
#pragma unroll
                    for (int c = 0; c < 2; ++c) {
                        const bf16x8 ah = c ? h1[B_] : h0[B_];
                        const bf16x8 al = c ? l1[B_] : l0[B_];
#pragma unroll
                        for (int ct = 0; ct < 8; ++ct) {
                            const bf16x8 b = lds_rd(smem, ct * 16 + ml,
                                                    g * 128 + c * 64 + q * 16, 1024);
                            acc[ct] = MFMA16(ah, b, acc[ct]);
                            acc[ct] = MFMA16(al, b, acc[ct]);
                        }
                    }
                }
            }

            // ---- epilogue: z partials, lane-pair packed u64 sc1 stores
#pragma unroll
            for (int ct = 0; ct < 8; ++ct)
#pragma unroll
                for (int r = 0; r < 4; ++r) {
                    const float v = acc[ct][r];
                    const float pv = __shfl_xor(v, 1, 64);
                    if (!(ml & 1)) {
                        const int row = w * 16 + q * 4 + r;
                        const int col = n0 + ct * 16 + ml;
                        ast64(&zpq[row * N5 + col], packf2(v, pv));
                    }
                }
            signal_flag(fA + bid * FPAD, t + 1);
        }
#undef LOADG
    } else {
        // ===== role B: gates (row rb) + agg-GEMM partial + exchange + state =====
        const int rb = bid - NBLK_A;         // also this block's P2 batch row
        const int cg = rb >> 2;              // agg col-group: cols cg*64..+63
        const int kq2 = rb & 3;              // agg K quarter: k kq2*768..+767
        const int nst = cg * 64 + kq2 * 16;  // state stripe: 16 u-cols
        const int KO = kq2 * 768;            // O k-slice base (elements)

        // stage aggT slice [64 cols][768 k] bf16, swizzled, rs=1536B
        for (int i = 0; i < 24; ++i) {
            const int cid = i * 256 + tid;   // 0..6143
            const int nloc = cid / 96, kc = cid - nloc * 96;
            const int k = kc * 8;
            bf16x8 v = *(const bf16x8*)(aggt + (size_t)(cg * 64 + nloc) * 3072 + KO + k);
            *(bf16x8*)(smem + nloc * 1536 + ((k * 2) ^ ((nloc & 7) << 4))) = v;
        }
        __syncthreads();

        const float s_ud = scal[0], s_ur = scal[1], s_ru = scal[2],
                    s_rd = scal[3], s_du = scal[4], s_dr = scal[5];
        const int rowA = w * 16 + ml;
        const bf16* orow = obuf + rowA * 3072 + KO;
        float* cpriv = c32 + rb * 1024;      // block-private [64 rows][16]
        float* pmy   = pbuf + (size_t)rb * 4096;

        for (int t = 0; t < TSTEPS; ++t) {
            wait_ge(fA, 96, t + 1);          // z cols 0..3071 ready (cg 0..23)
            // ---------------- P2: gates for batch row rb ----------------
            {
                f32x4 zu = {0.f,0.f,0.f,0.f}, zd = {0.f,0.f,0.f,0.f}, zn = {0.f,0.f,0.f,0.f};
#pragma unroll
                for (int kqi = 0; kqi < 4; ++kqi) {
                    const float* bp = zp + (size_t)kqi * 64 * N5 + rb * N5;
                    zu += ald_f4(bp + tid * 4);
                    zd += ald_f4(bp + U + tid * 4);
                    zn += ald_f4(bp + 2 * U + tid * 4);
                }
                zu += ((const f32x4*)bias)[tid];
                zd += ((const f32x4*)(bias + U))[tid];
                zn += ((const f32x4*)(bias + 2 * U))[tid];

                float mup = block_max(fmaxf(fmaxf(zu[0], zu[1]), fmaxf(zu[2], zu[3])), sm4, w, lane);
                const float e0 = __expf(zu[0] - mup), e1 = __expf(zu[1] - mup),
                            e2 = __expf(zu[2] - mup), e3 = __expf(zu[3] - mup);
                float totu;
                float inclu = block_scan(e0 + e1 + e2 + e3, sm4, w, lane, &totu);
                const float exclu = inclu - (e0 + e1 + e2 + e3);
                const float inv_u = 1.f / totu;
                const float u0 = (exclu + e0) * inv_u;
                const float u1 = (exclu + e0 + e1) * inv_u;
                const float u2 = (exclu + e0 + e1 + e2) * inv_u;
                const float u3 = (exclu + e0 + e1 + e2 + e3) * inv_u;

                float mdn = block_max(fmaxf(fmaxf(zd[0], zd[1]), fmaxf(zd[2], zd[3])), sm4, w, lane);
                const float f0 = __expf(zd[0] - mdn), f1 = __expf(zd[1] - mdn),
                            f2 = __expf(zd[2] - mdn), f3 = __expf(zd[3] - mdn);
                float totd;
                float incld = block_scan(f0 + f1 + f2 + f3, sm4, w, lane, &totd);
                const float excld = incld - (f0 + f1 + f2 + f3);
                const float inv_d = 1.f / totd;
                const float d0 = (totd - excld) * inv_d;
                const float d1 = (totd - excld - f0) * inv_d;
                const float d2 = (totd - excld - f0 - f1) * inv_d;
                const float d3 = (totd - excld - f0 - f1 - f2) * inv_d;

                const float du = block_sum(d0 * u0 + d1 * u1 + d2 * u2 + d3 * u3, sm4, w, lane);
                const float ru = block_sum(zn[0] * u0 + zn[1] * u1 + zn[2] * u2 + zn[3] * u3, sm4, w, lane);
                const float dr = block_sum(d0 * zn[0] + d1 * zn[1] + d2 * zn[2] + d3 * zn[3], sm4, w, lane);

                bf16* orw = obuf + rb * 3072;
                const int j0 = tid * 4;
                const float uu[4] = {u0, u1, u2, u3};
                const float dd[4] = {d0, d1, d2, d3};
                const float rr[4] = {zn[0], zn[1], zn[2], zn[3]};
                union { bf16 h[4]; u64 u; } p1, p2, p3;
#pragma unroll
                for (int i = 0; i < 4; ++i) {
                    p1.h[i] = __float2bfloat16(sigm(s_ud * uu[i] * du) + sigm(s_ur * uu[i] * ru));
                    p2.h[i] = __float2bfloat16(sigm(s_ru * rr[i] * ru) + sigm(s_rd * rr[i] * dr));
                    p3.h[i] = __float2bfloat16(sigm(s_du * dd[i] * du) + sigm(s_dr * dd[i] * dr));
                }
                ast64(orw + j0,         p1.u);
                ast64(orw + U + j0,     p2.u);
                ast64(orw + 2 * U + j0, p3.u);
            }
            signal_flag(fB + rb * FPAD, t + 1);

            // z3/z4 (flags 96..159): issue loads now so they fly under P3
            wait_ge(fA + 96 * FPAD, 64, t + 1);
            float z3v[4], z4v[4];
            {
                const int col = nst + ml;
                const int r0 = w * 16 + q * 4;
#pragma unroll
                for (int r = 0; r < 4; ++r) {
                    z3v[r] = bias[3 * U + col];
                    z4v[r] = bias[4 * U + col];
#pragma unroll
                    for (int kqi = 0; kqi < 4; ++kqi) {
                        const float* zr = zp + (size_t)kqi * 64 * N5 + (size_t)(r0 + r) * N5;
                        z3v[r] += ald_f(zr + 3 * U + col);
                        z4v[r] += ald_f(zr + 4 * U + col);
                    }
                }
            }
            wait_ge(fB, NBLK_B, t + 1);      // all O rows ready
            // -------- P3 partial: pf = O[:, KO:KO+768] @ aggT-slice --------
            {
                f32x4 acc[4];
#pragma unroll
                for (int i = 0; i < 4; ++i) acc[i] = (f32x4){0.f, 0.f, 0.f, 0.f};
                bf16x8 ob[3][8];
#pragma unroll
                for (int G = 0; G < 3; ++G)
#pragma unroll
                    for (int j = 0; j < 8; ++j)
                        ob[G][j] = ald16B(orow + (G * 8 + j) * 32 + q * 8);
#pragma unroll
                for (int g = 0; g < 3; ++g)
#pragma unroll
                    for (int j = 0; j < 8; ++j) {
                        const int kc = g * 8 + j;
#pragma unroll
                        for (int ct = 0; ct < 4; ++ct) {
                            const bf16x8 b = lds_rd(smem, ct * 16 + ml, kc * 64 + q * 16, 1536);
                            acc[ct] = MFMA16(ob[g][j], b, acc[ct]);
                        }
                    }
                // partial store: [64 rows][64 cols] f32, lane-pair packed
#pragma unroll
                for (int ct = 0; ct < 4; ++ct)
#pragma unroll
                    for (int r = 0; r < 4; ++r) {
                        const float v = acc[ct][r];
                        const float pv = __shfl_xor(v, 1, 64);
                        if (!(ml & 1)) {
                            const int row = w * 16 + q * 4 + r;
                            ast64(&pmy[row * 64 + ct * 16 + ml], packf2(v, pv));
                        }
                    }
            }
            signal_flag(fP + rb * FPAD, t + 1);
            wait_ge(fP + cg * 4 * FPAD, 4, t + 1);   // siblings' partials ready
            // -------- sum partials, f = sigm(.), state update, emit out --------
            {
                const int col = nst + ml;
                const int r0 = w * 16 + q * 4;
#pragma unroll
                for (int r = 0; r < 4; ++r) {
                    const int row = r0 + r;
                    float s = 0.f;
#pragma unroll
                    for (int j = 0; j < 4; ++j)
                        s += ald_f(pbuf + (size_t)(cg * 4 + j) * 4096 + row * 64 + kq2 * 16 + ml);
                    const float f = sigm(s);
                    const float cold = cpriv[row * 16 + ml];
                    const float cn = f * cold + (1.f - f) * tanhf(z4v[r]);
                    const float hn = z3v[r] * tanhf(cn);
                    cpriv[row * 16 + ml] = cn;
                    const bf16 chb = __float2bfloat16(cn);
                    const bf16 clb = __float2bfloat16(cn - __bfloat162float(chb));
                    const bf16 hhb = __float2bfloat16(hn);
                    const bf16 hlb = __float2bfloat16(hn - __bfloat162float(hhb));
                    unsigned vh = bfbits(hhb), vl = bfbits(hlb),
                             vc = bfbits(chb), vx = bfbits(clb);
                    const unsigned ph = (unsigned)__shfl_xor((int)vh, 1, 64);
                    const unsigned pl = (unsigned)__shfl_xor((int)vl, 1, 64);
                    const unsigned pc = (unsigned)__shfl_xor((int)vc, 1, 64);
                    const unsigned px = (unsigned)__shfl_xor((int)vx, 1, 64);
                    if (!(ml & 1)) {
                        const int eo = row * U + col;
                        ast32((unsigned*)(abuf + 0 * 65536 + eo), vh | (ph << 16));
                        ast32((unsigned*)(abuf + 1 * 65536 + eo), vl | (pl << 16));
                        ast32((unsigned*)(abuf + 2 * 65536 + eo), vc | (pc << 16));
                        ast32((unsigned*)(abuf + 3 * 65536 + eo), vx | (px << 16));
                    }
                    out[((size_t)row * TSTEPS + t) * U + col] = hn;
                }
            }
            signal_flag(fC + rb * FPAD, t + 1);
        }
    }
}

// ---------------------------------------------------------------------------
extern "C" void kernel_launch(void* const* d_in, const int* in_sizes, int n_in,
                              void* d_out, int out_size, void* d_ws, size_t ws_size,
                              hipStream_t stream) {
    (void)in_sizes; (void)n_in; (void)out_size; (void)ws_size;
    const float* x    = (const float*)d_in[0];
    const float* Wk   = (const float*)d_in[1];   // (256,5120)
    const float* Wr   = (const float*)d_in[2];   // (1024,5120)
    const float* Wc   = (const float*)d_in[3];   // (1024,5120)
    const float* bias = (const float*)d_in[4];   // (5120)
    const float* agg  = (const float*)d_in[5];   // (3072,1024)

    char* ws = (char*)d_ws;
    bf16*  wrct = (bf16*)(ws + OFF_WRC);
    bf16*  kt   = (bf16*)(ws + OFF_KT);
    bf16*  aggt = (bf16*)(ws + OFF_AGGT);
    bf16*  xbf  = (bf16*)(ws + OFF_XBF);
    float* zp   = (float*)(ws + OFF_ZP);
    bf16*  abuf = (bf16*)(ws + OFF_ABUF);
    float* c32  = (float*)(ws + OFF_C32);
    bf16*  obuf = (bf16*)(ws + OFF_OBUF);
    float* pbuf = (float*)(ws + OFF_PB);     // overlays kt (dead after staging)
    float* scal = (float*)(ws + OFF_SCAL);
    int*   ctr  = (int*)(ws + OFF_CTR);
    float* out  = (float*)d_out;

    hipMemsetAsync(abuf, 0, 4 * 65536 * sizeof(bf16), stream);
    hipMemsetAsync(c32, 0, BATCH * U * sizeof(float), stream);
    hipMemsetAsync(ctr, 0, 12288, stream);   // flag zone reset each launch

    // one-time conversions / transposes
    k_xconv<<<(BATCH * TSTEPS * DIM / 4 + 255) / 256, 256, 0, stream>>>(x, xbf, BATCH * TSTEPS * DIM / 4);
    k_transpose<<<dim3(5120 / 64, 1024 / 64), 256, 0, stream>>>(Wr, wrct, 5120, 2048, 0);
    k_transpose<<<dim3(5120 / 64, 1024 / 64), 256, 0, stream>>>(Wc, wrct, 5120, 2048, 1024);
    k_transpose<<<dim3(5120 / 64, 256 / 64),  256, 0, stream>>>(Wk, kt,   5120, 256, 0);
    k_transpose<<<dim3(1024 / 64, 3072 / 64), 256, 0, stream>>>(agg, aggt, 1024, 3072, 0);

    AttPtrs ap;
    for (int i = 0; i < 12; ++i) ap.p[i] = (const float*)d_in[6 + i];
    k_scal<<<1, 256, 0, stream>>>(ap, scal);

    // the whole recurrence: one persistent launch
    k_persist<<<NBLK, 256, 0, stream>>>(xbf, kt, wrct, aggt, zp, abuf, c32,
                                        obuf, pbuf, scal, bias, out, ctr);
}

// Round 7
// 3384.759 us; speedup vs baseline: 2.6925x; 1.1390x over previous
//
#include <hip/hip_runtime.h>
#include <hip/hip_bf16.h>

// ---------------------------------------------------------------------------
// MA_LSTM on MI355X (gfx950) — persistent kernel, v7: fp16 state/weights.
// v6 post-mortem: step = coherent-path bytes + hops; largest stream = A-role
// h/c hi/lo bf16 (20.5 MB/step, and 2x the MFMAs). v7: h,c,x,Wk,Wr,Wc all
// fp16 (mfma_f32_16x16x32_f16, same rate): |c|<=1, |h|=O(1) fit fp16; 11-bit
// mantissa beats the old plain-bf16 WEIGHTS (8-bit) that dominated error.
// Halves A-stream bytes (10.2 MB/step), load ops, and A MFMA count. f32 z
// partials / gates / c-state and the bf16 O@agg path unchanged.
//   blocks 0..159 ("A"): z-GEMM partials (40 col-groups x 4 K-quarters).
//   blocks 160..223 ("B"): gates (row rb) + agg-GEMM partial (64c x 768k)
//                          + partial exchange + state update (16 cols).
// Fence-free: cross-block data via relaxed AGENT-scope atomics (sc1).
// ---------------------------------------------------------------------------

typedef short  bf16x8 __attribute__((ext_vector_type(8)));
typedef float  f32x4  __attribute__((ext_vector_type(4)));
typedef _Float16 f16;
typedef _Float16 f16x8 __attribute__((ext_vector_type(8)));
typedef __hip_bfloat16 bf16;
typedef unsigned long long u64;

#define U 1024
#define BATCH 64
#define TSTEPS 128
#define DIM 256
#define N5 5120
#define K2 2048   // h(1024) + c(1024)

// ---- workspace layout (bytes) ----
#define OFF_WRC   0u                       // f16  [5120][2048]  (Wr^T | Wc^T)
#define OFF_KT    20971520u                // f16  [5120][256]   kernel^T (staging only)
#define OFF_AGGT  23592960u                // bf16 [1024][3072]  aggregation^T
#define OFF_XBF   29884416u                // f16  [64][128][256] x in fp16
#define OFF_ZP    34078720u                // f32  [4][64][5120] z partials
#define OFF_ABUF  39321600u                // f16  [2][64][1024] h, c
#define OFF_C32   39845888u                // f32  c state (block-private stripes)
#define OFF_OBUF  40108032u                // bf16 [64][3072]
#define OFF_SCAL  40501248u                // f32  [8]
#define OFF_CTR   40501504u                // int flags (12KB zone, 32B-padded)
#define OFF_PB    OFF_KT                   // f32 [64][64][64] f-partials (kt dead after staging)

#define NBLK_A 160
#define NBLK_B 64
#define NBLK   224
#define FPAD   8      // ints between flags (32B)

#define KT_OFF 131072 // LDS byte offset of kt slab in A-role

#define MFMA16(a,b,c)  __builtin_amdgcn_mfma_f32_16x16x32_bf16((a),(b),(c),0,0,0)
#define MFMA16H(a,b,c) __builtin_amdgcn_mfma_f32_16x16x32_f16((a),(b),(c),0,0,0)

// ---------------------------------------------------------------------------
__global__ __launch_bounds__(256) void k_xconv(const float* __restrict__ in,
                                               f16* __restrict__ o, int n4) {
    const int i = blockIdx.x * 256 + threadIdx.x;
    if (i < n4) {
        const float4 v = ((const float4*)in)[i];
        f16 tmp[4] = {(f16)v.x, (f16)v.y, (f16)v.z, (f16)v.w};
        ((uint2*)o)[i] = *(const uint2*)tmp;
    }
}

// ---------------------------------------------------------------------------
// tiled transpose + fp32->fp16
__global__ __launch_bounds__(256) void k_transpose_h(const float* __restrict__ in,
                                                     f16* __restrict__ out,
                                                     int C, int out_stride, int out_off) {
    __shared__ f16 tile[64][65];
    const int tc = blockIdx.x * 64, tr = blockIdx.y * 64;
    const int tx = threadIdx.x & 63, ty0 = threadIdx.x >> 6;
#pragma unroll
    for (int i = 0; i < 64; i += 4)
        tile[ty0 + i][tx] = (f16)(in[(tr + ty0 + i) * C + tc + tx]);
    __syncthreads();
#pragma unroll
    for (int i = 0; i < 64; i += 4)
        out[(tc + ty0 + i) * out_stride + out_off + tr + tx] = tile[tx][ty0 + i];
}

// tiled transpose + fp32->bf16 (agg only)
__global__ __launch_bounds__(256) void k_transpose_b(const float* __restrict__ in,
                                                     bf16* __restrict__ out,
                                                     int C, int out_stride, int out_off) {
    __shared__ bf16 tile[64][65];
    const int tc = blockIdx.x * 64, tr = blockIdx.y * 64;
    const int tx = threadIdx.x & 63, ty0 = threadIdx.x >> 6;
#pragma unroll
    for (int i = 0; i < 64; i += 4)
        tile[ty0 + i][tx] = __float2bfloat16(in[(tr + ty0 + i) * C + tc + tx]);
    __syncthreads();
#pragma unroll
    for (int i = 0; i < 64; i += 4)
        out[(tc + ty0 + i) * out_stride + out_off + tr + tx] = tile[tx][ty0 + i];
}

// ---------------------------------------------------------------------------
struct AttPtrs { const float* p[12]; };

__global__ __launch_bounds__(256) void k_scal(AttPtrs ap, float* __restrict__ scal) {
    __shared__ float red[256];
    const int tid = threadIdx.x;
    for (int q = 0; q < 6; ++q) {
        const float* l = ap.p[2 * q];
        const float* r = ap.p[2 * q + 1];
        float s = 0.f;
        for (int i = tid; i < 1024; i += 256)
            s += l[i] * r[i];
        red[tid] = s; __syncthreads();
        for (int o = 128; o > 0; o >>= 1) {
            if (tid < o) red[tid] += red[tid + o];
            __syncthreads();
        }
        if (tid == 0) scal[q] = red[0];
        __syncthreads();
    }
}

// ---------------------------------------------------------------------------
// block collectives (256 threads = 4 waves)
__device__ __forceinline__ float wave_sum(float v) {
#pragma unroll
    for (int o = 32; o > 0; o >>= 1) v += __shfl_xor(v, o, 64);
    return v;
}
__device__ __forceinline__ float wave_max(float v) {
#pragma unroll
    for (int o = 32; o > 0; o >>= 1) v = fmaxf(v, __shfl_xor(v, o, 64));
    return v;
}
__device__ __forceinline__ float wave_scan(float v, int lane) {
#pragma unroll
    for (int o = 1; o < 64; o <<= 1) {
        float n = __shfl_up(v, o, 64);
        if (lane >= o) v += n;
    }
    return v;
}
__device__ __forceinline__ float block_sum(float v, float* sm4, int w, int lane) {
    float s = wave_sum(v);
    if (lane == 0) sm4[w] = s;
    __syncthreads();
    float r = sm4[0] + sm4[1] + sm4[2] + sm4[3];
    __syncthreads();
    return r;
}
__device__ __forceinline__ float block_max(float v, float* sm4, int w, int lane) {
    float s = wave_max(v);
    if (lane == 0) sm4[w] = s;
    __syncthreads();
    float r = fmaxf(fmaxf(sm4[0], sm4[1]), fmaxf(sm4[2], sm4[3]));
    __syncthreads();
    return r;
}
__device__ __forceinline__ float block_scan(float v, float* sm4, int w, int lane, float* total) {
    float ws = wave_scan(v, lane);
    if (lane == 63) sm4[w] = ws;
    __syncthreads();
    float base = 0.f;
    if (w > 0) base += sm4[0];
    if (w > 1) base += sm4[1];
    if (w > 2) base += sm4[2];
    *total = sm4[0] + sm4[1] + sm4[2] + sm4[3];
    __syncthreads();
    return base + ws;
}
__device__ __forceinline__ float sigm(float x) { return 1.f / (1.f + __expf(-x)); }

// ---------------------------------------------------------------------------
// sc1 (coherence-point) data path: relaxed agent-scope atomics.
__device__ __forceinline__ u64 ald64(const void* p) {
    return __hip_atomic_load((const u64*)p, __ATOMIC_RELAXED, __HIP_MEMORY_SCOPE_AGENT);
}
__device__ __forceinline__ bf16x8 ald16B(const bf16* p) {
    union { bf16x8 v; u64 u[2]; } r;
    r.u[0] = ald64(p);
    r.u[1] = ald64((const char*)p + 8);
    return r.v;
}
__device__ __forceinline__ f16x8 aldh16B(const f16* p) {
    union { f16x8 v; u64 u[2]; } r;
    r.u[0] = ald64(p);
    r.u[1] = ald64((const char*)p + 8);
    return r.v;
}
__device__ __forceinline__ f32x4 ald_f4(const float* p) {
    union { f32x4 v; u64 u[2]; } r;
    r.u[0] = ald64(p);
    r.u[1] = ald64(p + 2);
    return r.v;
}
__device__ __forceinline__ float ald_f(const float* p) {
    return __hip_atomic_load(p, __ATOMIC_RELAXED, __HIP_MEMORY_SCOPE_AGENT);
}
__device__ __forceinline__ void ast64(void* p, u64 v) {
    __hip_atomic_store((u64*)p, v, __ATOMIC_RELAXED, __HIP_MEMORY_SCOPE_AGENT);
}
__device__ __forceinline__ void ast32(void* p, unsigned v) {
    __hip_atomic_store((unsigned*)p, v, __ATOMIC_RELAXED, __HIP_MEMORY_SCOPE_AGENT);
}
__device__ __forceinline__ unsigned h16bits(f16 h) {
    unsigned short s; __builtin_memcpy(&s, &h, 2); return (unsigned)s;
}
__device__ __forceinline__ u64 packf2(float a, float b) {
    union { float f[2]; u64 u; } r; r.f[0] = a; r.f[1] = b; return r.u;
}

// flag barriers, fence-free (see v3 comment)
__device__ __forceinline__ void signal_flag(int* f, int v) {
    __syncthreads();
    if (threadIdx.x == 0)
        __hip_atomic_store(f, v, __ATOMIC_RELAXED, __HIP_MEMORY_SCOPE_AGENT);
}
__device__ __forceinline__ void wait_ge(const int* f, int n, int tgt) {
    if (threadIdx.x < 64) {
        for (;;) {
            int mn = 0x7fffffff;
            for (int i = threadIdx.x; i < n; i += 64) {
                const int v = __hip_atomic_load(f + i * FPAD, __ATOMIC_RELAXED,
                                                __HIP_MEMORY_SCOPE_AGENT);
                mn = v < mn ? v : mn;
            }
            if (__all(mn >= tgt)) break;
            __builtin_amdgcn_s_sleep(1);
        }
    }
    __syncthreads();
}

// swizzled LDS reads
__device__ __forceinline__ bf16x8 lds_rd(const char* s, int nloc, int kb, int rs) {
    return *(const bf16x8*)(s + nloc * rs + (kb ^ ((nloc & 7) << 4)));
}
__device__ __forceinline__ f16x8 lds_rdh(const char* s, int nloc, int kb, int rs) {
    return *(const f16x8*)(s + nloc * rs + (kb ^ ((nloc & 7) << 4)));
}

// ---------------------------------------------------------------------------
__global__ __launch_bounds__(256, 1) void k_persist(
    const f16* __restrict__ xbf, const f16* __restrict__ kt,
    const f16* __restrict__ wrct, const bf16* __restrict__ aggt,
    float* __restrict__ zp, f16* __restrict__ abuf,
    float* __restrict__ c32, bf16* __restrict__ obuf,
    float* __restrict__ pbuf,
    const float* __restrict__ scal, const float* __restrict__ bias,
    float* __restrict__ out, int* __restrict__ ctr)
{
    __shared__ __align__(16) char smem[147456];   // A: 128KB weights + 16KB kt; B: 96KB aggT slice
    __shared__ float sm4[4];

    const int bid = blockIdx.x, tid = threadIdx.x;
    const int w = tid >> 6, lane = tid & 63;
    const int ml = lane & 15, q = lane >> 4;
    int* fA = ctr;            // [160*FPAD] z-partials ready (value t+1)
    int* fB = ctr + 1280;     // [64*FPAD]  O rows ready
    int* fC = ctr + 1792;     // [64*FPAD]  h,c state ready
    int* fP = ctr + 2304;     // [64*FPAD]  f-partials ready

    if (bid < NBLK_A) {
        // =================== role A: z-GEMM partial ====================
        const int cg = bid >> 2;            // col group: cols cg*128..+127
        const int kq = bid & 3;             // K quarter: 0,1=h halves; 2,3=c halves
        const int n0 = cg * 128;
        const int kwbase = (kq < 2) ? kq * 512 : 1024 + (kq - 2) * 512;
        const int kA0 = (kq & 1) * 512;     // offset within h (or c) plane

        // stage weights [128 cols][512 k] f16, swizzled, rs=1024B
        for (int i = 0; i < 32; ++i) {
            const int cid = i * 256 + tid;
            const int row = cid >> 6, k = (cid & 63) * 8;
            f16x8 v = *(const f16x8*)(wrct + (size_t)(n0 + row) * K2 + kwbase + k);
            *(f16x8*)(smem + row * 1024 + ((k * 2) ^ ((row & 7) << 4))) = v;
        }
        // stage kt slab [128 cols][64 k] f16, swizzled, rs=128B
        for (int i = 0; i < 4; ++i) {
            const int cid = i * 256 + tid;
            const int row = cid >> 3, k = (cid & 7) * 8;
            f16x8 v = *(const f16x8*)(kt + (size_t)(n0 + row) * DIM + kq * 64 + k);
            *(f16x8*)(smem + KT_OFF + row * 128 + ((k * 2) ^ ((row & 7) << 4))) = v;
        }
        __syncthreads();

        const int arow = w * 16 + ml;       // this lane's batch row (A-frag row)
        const f16* hP = abuf + (kq < 2 ? 0 : 1) * 65536 + arow * U + kA0;
        const f16* xrow = xbf + (size_t)arow * TSTEPS * DIM;
        float* zpq = zp + (size_t)kq * 64 * N5;

#define LOADG(G, B) do { \
            const int b_ = (G) * 64 + q * 8; \
            a0[B] = aldh16B(hP + b_); \
            a1[B] = aldh16B(hP + b_ + 32); \
        } while (0)

        for (int t = 0; t < TSTEPS; ++t) {
            f32x4 acc[8];
#pragma unroll
            for (int i = 0; i < 8; ++i) acc[i] = (f32x4){0.f, 0.f, 0.f, 0.f};

            // ---- x @ kernel slice (64 k): independent of state, before wait
#pragma unroll
            for (int cx = 0; cx < 2; ++cx) {
                const f16x8 ax = *(const f16x8*)(xrow + t * DIM + kq * 64 + cx * 32 + q * 8);
#pragma unroll
                for (int ct = 0; ct < 8; ++ct) {
                    const f16x8 b = lds_rdh(smem + KT_OFF, ct * 16 + ml, cx * 64 + q * 16, 128);
                    acc[ct] = MFMA16H(ax, b, acc[ct]);
                }
            }

            wait_ge(fC, NBLK_B, t);          // state of step t-1 ready

            // ---- (h|c) quarter fp16: 8 k-groups of 64, 4-deep ring,
            //      distance-3 prefetch (load (g+3)&3, consume g&3 — disjoint)
            {
                f16x8 a0[4], a1[4];
                LOADG(0, 0);
                LOADG(1, 1);
                LOADG(2, 2);
#pragma unroll
                for (int g = 0; g < 8; ++g) {
                    if (g < 5) LOADG(g + 3, (g + 3) & 3);
                    const int B_ = g & 3;
#pragma unroll
                    for (int c = 0; c < 2; ++c) {
                        const f16x8 a = c ? a1[B_] : a0[B_];
#pragma unroll
                        for (int ct = 0; ct < 8; ++ct) {
                            const f16x8 b = lds_rdh(smem, ct * 16 + ml,
                                                    g * 128 + c * 64 + q * 16, 1024);
                            acc[ct] = MFMA16H(a, b, acc[ct]);
                        }
                    }
                }
            }

            // ---- epilogue: z partials, lane-pair packed u64 sc1 stores
#pragma unroll
            for (int ct = 0; ct < 8; ++ct)
#pragma unroll
                for (int r = 0; r < 4; ++r) {
                    const float v = acc[ct][r];
                    const float pv = __shfl_xor(v, 1, 64);
                    if (!(ml & 1)) {
                        const int row = w * 16 + q * 4 + r;
                        const int col = n0 + ct * 16 + ml;
                        ast64(&zpq[row * N5 + col], packf2(v, pv));
                    }
                }
            signal_flag(fA + bid * FPAD, t + 1);
        }
#undef LOADG
    } else {
        // ===== role B: gates (row rb) + agg-GEMM partial + exchange + state =====
        const int rb = bid - NBLK_A;         // also this block's P2 batch row
        const int cg = rb >> 2;              // agg col-group: cols cg*64..+63
        const int kq2 = rb & 3;              // agg K quarter: k kq2*768..+767
        const int nst = cg * 64 + kq2 * 16;  // state stripe: 16 u-cols
        const int KO = kq2 * 768;            // O k-slice base (elements)

        // stage aggT slice [64 cols][768 k] bf16, swizzled, rs=1536B
        for (int i = 0; i < 24; ++i) {
            const int cid = i * 256 + tid;   // 0..6143
            const int nloc = cid / 96, kc = cid - nloc * 96;
            const int k = kc * 8;
            bf16x8 v = *(const bf16x8*)(aggt + (size_t)(cg * 64 + nloc) * 3072 + KO + k);
            *(bf16x8*)(smem + nloc * 1536 + ((k * 2) ^ ((nloc & 7) << 4))) = v;
        }
        __syncthreads();

        const float s_ud = scal[0], s_ur = scal[1], s_ru = scal[2],
                    s_rd = scal[3], s_du = scal[4], s_dr = scal[5];
        const int rowA = w * 16 + ml;
        const bf16* orow = obuf + rowA * 3072 + KO;
        float* cpriv = c32 + rb * 1024;      // block-private [64 rows][16]
        float* pmy   = pbuf + (size_t)rb * 4096;

        for (int t = 0; t < TSTEPS; ++t) {
            wait_ge(fA, 96, t + 1);          // z cols 0..3071 ready (cg 0..23)
            // ---------------- P2: gates for batch row rb ----------------
            {
                f32x4 zu = {0.f,0.f,0.f,0.f}, zd = {0.f,0.f,0.f,0.f}, zn = {0.f,0.f,0.f,0.f};
#pragma unroll
                for (int kqi = 0; kqi < 4; ++kqi) {
                    const float* bp = zp + (size_t)kqi * 64 * N5 + rb * N5;
                    zu += ald_f4(bp + tid * 4);
                    zd += ald_f4(bp + U + tid * 4);
                    zn += ald_f4(bp + 2 * U + tid * 4);
                }
                zu += ((const f32x4*)bias)[tid];
                zd += ((const f32x4*)(bias + U))[tid];
                zn += ((const f32x4*)(bias + 2 * U))[tid];

                float mup = block_max(fmaxf(fmaxf(zu[0], zu[1]), fmaxf(zu[2], zu[3])), sm4, w, lane);
                const float e0 = __expf(zu[0] - mup), e1 = __expf(zu[1] - mup),
                            e2 = __expf(zu[2] - mup), e3 = __expf(zu[3] - mup);
                float totu;
                float inclu = block_scan(e0 + e1 + e2 + e3, sm4, w, lane, &totu);
                const float exclu = inclu - (e0 + e1 + e2 + e3);
                const float inv_u = 1.f / totu;
                const float u0 = (exclu + e0) * inv_u;
                const float u1 = (exclu + e0 + e1) * inv_u;
                const float u2 = (exclu + e0 + e1 + e2) * inv_u;
                const float u3 = (exclu + e0 + e1 + e2 + e3) * inv_u;

                float mdn = block_max(fmaxf(fmaxf(zd[0], zd[1]), fmaxf(zd[2], zd[3])), sm4, w, lane);
                const float f0 = __expf(zd[0] - mdn), f1 = __expf(zd[1] - mdn),
                            f2 = __expf(zd[2] - mdn), f3 = __expf(zd[3] - mdn);
                float totd;
                float incld = block_scan(f0 + f1 + f2 + f3, sm4, w, lane, &totd);
                const float excld = incld - (f0 + f1 + f2 + f3);
                const float inv_d = 1.f / totd;
                const float d0 = (totd - excld) * inv_d;
                const float d1 = (totd - excld - f0) * inv_d;
                const float d2 = (totd - excld - f0 - f1) * inv_d;
                const float d3 = (totd - excld - f0 - f1 - f2) * inv_d;

                const float du = block_sum(d0 * u0 + d1 * u1 + d2 * u2 + d3 * u3, sm4, w, lane);
                const float ru = block_sum(zn[0] * u0 + zn[1] * u1 + zn[2] * u2 + zn[3] * u3, sm4, w, lane);
                const float dr = block_sum(d0 * zn[0] + d1 * zn[1] + d2 * zn[2] + d3 * zn[3], sm4, w, lane);

                bf16* orw = obuf + rb * 3072;
                const int j0 = tid * 4;
                const float uu[4] = {u0, u1, u2, u3};
                const float dd[4] = {d0, d1, d2, d3};
                const float rr[4] = {zn[0], zn[1], zn[2], zn[3]};
                union { bf16 h[4]; u64 u; } p1, p2, p3;
#pragma unroll
                for (int i = 0; i < 4; ++i) {
                    p1.h[i] = __float2bfloat16(sigm(s_ud * uu[i] * du) + sigm(s_ur * uu[i] * ru));
                    p2.h[i] = __float2bfloat16(sigm(s_ru * rr[i] * ru) + sigm(s_rd * rr[i] * dr));
                    p3.h[i] = __float2bfloat16(sigm(s_du * dd[i] * du) + sigm(s_dr * dd[i] * dr));
                }
                ast64(orw + j0,         p1.u);
                ast64(orw + U + j0,     p2.u);
                ast64(orw + 2 * U + j0, p3.u);
            }
            signal_flag(fB + rb * FPAD, t + 1);

            // z3/z4 (flags 96..159): issue loads now so they fly under P3
            wait_ge(fA + 96 * FPAD, 64, t + 1);
            float z3v[4], z4v[4];
            {
                const int col = nst + ml;
                const int r0 = w * 16 + q * 4;
#pragma unroll
                for (int r = 0; r < 4; ++r) {
                    z3v[r] = bias[3 * U + col];
                    z4v[r] = bias[4 * U + col];
#pragma unroll
                    for (int kqi = 0; kqi < 4; ++kqi) {
                        const float* zr = zp + (size_t)kqi * 64 * N5 + (size_t)(r0 + r) * N5;
                        z3v[r] += ald_f(zr + 3 * U + col);
                        z4v[r] += ald_f(zr + 4 * U + col);
                    }
                }
            }
            wait_ge(fB, NBLK_B, t + 1);      // all O rows ready
            // -------- P3 partial: pf = O[:, KO:KO+768] @ aggT-slice --------
            {
                f32x4 acc[4];
#pragma unroll
                for (int i = 0; i < 4; ++i) acc[i] = (f32x4){0.f, 0.f, 0.f, 0.f};
                bf16x8 ob[3][8];
#pragma unroll
                for (int G = 0; G < 3; ++G)
#pragma unroll
                    for (int j = 0; j < 8; ++j)
                        ob[G][j] = ald16B(orow + (G * 8 + j) * 32 + q * 8);
#pragma unroll
                for (int g = 0; g < 3; ++g)
#pragma unroll
                    for (int j = 0; j < 8; ++j) {
                        const int kc = g * 8 + j;
#pragma unroll
                        for (int ct = 0; ct < 4; ++ct) {
                            const bf16x8 b = lds_rd(smem, ct * 16 + ml, kc * 64 + q * 16, 1536);
                            acc[ct] = MFMA16(ob[g][j], b, acc[ct]);
                        }
                    }
                // partial store: [64 rows][64 cols] f32, lane-pair packed
#pragma unroll
                for (int ct = 0; ct < 4; ++ct)
#pragma unroll
                    for (int r = 0; r < 4; ++r) {
                        const float v = acc[ct][r];
                        const float pv = __shfl_xor(v, 1, 64);
                        if (!(ml & 1)) {
                            const int row = w * 16 + q * 4 + r;
                            ast64(&pmy[row * 64 + ct * 16 + ml], packf2(v, pv));
                        }
                    }
            }
            signal_flag(fP + rb * FPAD, t + 1);
            wait_ge(fP + cg * 4 * FPAD, 4, t + 1);   // siblings' partials ready
            // -------- sum partials, f = sigm(.), state update, emit out --------
            {
                const int col = nst + ml;
                const int r0 = w * 16 + q * 4;
#pragma unroll
                for (int r = 0; r < 4; ++r) {
                    const int row = r0 + r;
                    float s = 0.f;
#pragma unroll
                    for (int j = 0; j < 4; ++j)
                        s += ald_f(pbuf + (size_t)(cg * 4 + j) * 4096 + row * 64 + kq2 * 16 + ml);
                    const float f = sigm(s);
                    const float cold = cpriv[row * 16 + ml];
                    const float cn = f * cold + (1.f - f) * tanhf(z4v[r]);
                    const float hn = z3v[r] * tanhf(cn);
                    cpriv[row * 16 + ml] = cn;
                    const f16 hhb = (f16)hn;
                    const f16 ccb = (f16)cn;
                    unsigned vh = h16bits(hhb), vc = h16bits(ccb);
                    const unsigned ph = (unsigned)__shfl_xor((int)vh, 1, 64);
                    const unsigned pc = (unsigned)__shfl_xor((int)vc, 1, 64);
                    if (!(ml & 1)) {
                        const int eo = row * U + col;
                        ast32((unsigned*)(abuf + 0 * 65536 + eo), vh | (ph << 16));
                        ast32((unsigned*)(abuf + 1 * 65536 + eo), vc | (pc << 16));
                    }
                    out[((size_t)row * TSTEPS + t) * U + col] = hn;
                }
            }
            signal_flag(fC + rb * FPAD, t + 1);
        }
    }
}

// ---------------------------------------------------------------------------
extern "C" void kernel_launch(void* const* d_in, const int* in_sizes, int n_in,
                              void* d_out, int out_size, void* d_ws, size_t ws_size,
                              hipStream_t stream) {
    (void)in_sizes; (void)n_in; (void)out_size; (void)ws_size;
    const float* x    = (const float*)d_in[0];
    const float* Wk   = (const float*)d_in[1];   // (256,5120)
    const float* Wr   = (const float*)d_in[2];   // (1024,5120)
    const float* Wc   = (const float*)d_in[3];   // (1024,5120)
    const float* bias = (const float*)d_in[4];   // (5120)
    const float* agg  = (const float*)d_in[5];   // (3072,1024)

    char* ws = (char*)d_ws;
    f16*   wrct = (f16*)(ws + OFF_WRC);
    f16*   kt   = (f16*)(ws + OFF_KT);
    bf16*  aggt = (bf16*)(ws + OFF_AGGT);
    f16*   xbf  = (f16*)(ws + OFF_XBF);
    float* zp   = (float*)(ws + OFF_ZP);
    f16*   abuf = (f16*)(ws + OFF_ABUF);
    float* c32  = (float*)(ws + OFF_C32);
    bf16*  obuf = (bf16*)(ws + OFF_OBUF);
    float* pbuf = (float*)(ws + OFF_PB);     // overlays kt (dead after staging)
    float* scal = (float*)(ws + OFF_SCAL);
    int*   ctr  = (int*)(ws + OFF_CTR);
    float* out  = (float*)d_out;

    hipMemsetAsync(abuf, 0, 2 * 65536 * sizeof(f16), stream);
    hipMemsetAsync(c32, 0, BATCH * U * sizeof(float), stream);
    hipMemsetAsync(ctr, 0, 12288, stream);   // flag zone reset each launch

    // one-time conversions / transposes
    k_xconv<<<(BATCH * TSTEPS * DIM / 4 + 255) / 256, 256, 0, stream>>>(x, xbf, BATCH * TSTEPS * DIM / 4);
    k_transpose_h<<<dim3(5120 / 64, 1024 / 64), 256, 0, stream>>>(Wr, wrct, 5120, 2048, 0);
    k_transpose_h<<<dim3(5120 / 64, 1024 / 64), 256, 0, stream>>>(Wc, wrct, 5120, 2048, 1024);
    k_transpose_h<<<dim3(5120 / 64, 256 / 64),  256, 0, stream>>>(Wk, kt,   5120, 256, 0);
    k_transpose_b<<<dim3(1024 / 64, 3072 / 64), 256, 0, stream>>>(agg, aggt, 1024, 3072, 0);

    AttPtrs ap;
    for (int i = 0; i < 12; ++i) ap.p[i] = (const float*)d_in[6 + i];
    k_scal<<<1, 256, 0, stream>>>(ap, scal);

    // the whole recurrence: one persistent launch
    k_persist<<<NBLK, 256, 0, stream>>>(xbf, kt, wrct, aggt, zp, abuf, c32,
                                        obuf, pbuf, scal, bias, out, ctr);
}

// Round 8
// 3363.279 us; speedup vs baseline: 2.7097x; 1.0064x over previous
//
#include <hip/hip_runtime.h>
#include <hip/hip_bf16.h>

// ---------------------------------------------------------------------------
// MA_LSTM on MI355X (gfx950) — persistent kernel, v8: max loads-in-flight.
// v7 post-mortem: phases are LATENCY-bound bursts of sc1 (coherence-point)
// loads (~1us-class cross-chiplet). v8: (1) A-role loads ALL 16 h/c 16B
// chunks at once (32 sc1 loads in flight) and runs the x@kt MFMAs (LDS-only)
// under them; (2) A waits only the 32 fC stripes covering its k-range;
// (3) pbuf relayout [cg][row][col][j] -> state gather = 4 f32x4 loads
// (was 16 scalars); (4) out-store after fC signal (out of the vmcnt drain).
//   blocks 0..159 ("A"): z-GEMM partials (40 col-groups x 4 K-quarters).
//   blocks 160..223 ("B"): gates (row rb) + agg-GEMM partial (64c x 768k)
//                          + partial exchange + state update (16 cols).
// Fence-free: cross-block data via relaxed AGENT-scope atomics (sc1).
// ---------------------------------------------------------------------------

typedef short  bf16x8 __attribute__((ext_vector_type(8)));
typedef float  f32x4  __attribute__((ext_vector_type(4)));
typedef _Float16 f16;
typedef _Float16 f16x8 __attribute__((ext_vector_type(8)));
typedef __hip_bfloat16 bf16;
typedef unsigned long long u64;

#define U 1024
#define BATCH 64
#define TSTEPS 128
#define DIM 256
#define N5 5120
#define K2 2048   // h(1024) + c(1024)

// ---- workspace layout (bytes) ----
#define OFF_WRC   0u                       // f16  [5120][2048]  (Wr^T | Wc^T)
#define OFF_KT    20971520u                // f16  [5120][256]   kernel^T (staging only)
#define OFF_AGGT  23592960u                // bf16 [1024][3072]  aggregation^T
#define OFF_XBF   29884416u                // f16  [64][128][256] x in fp16
#define OFF_ZP    34078720u                // f32  [4][64][5120] z partials
#define OFF_ABUF  39321600u                // f16  [2][64][1024] h, c
#define OFF_C32   39845888u                // f32  c state (block-private stripes)
#define OFF_OBUF  40108032u                // bf16 [64][3072]
#define OFF_SCAL  40501248u                // f32  [8]
#define OFF_CTR   40501504u                // int flags (12KB zone, 32B-padded)
#define OFF_PB    OFF_KT                   // f32 [16cg][64row][64col][4j] (kt dead after staging)

#define NBLK_A 160
#define NBLK_B 64
#define NBLK   224
#define FPAD   8      // ints between flags (32B)

#define KT_OFF 131072 // LDS byte offset of kt slab in A-role

#define MFMA16(a,b,c)  __builtin_amdgcn_mfma_f32_16x16x32_bf16((a),(b),(c),0,0,0)
#define MFMA16H(a,b,c) __builtin_amdgcn_mfma_f32_16x16x32_f16((a),(b),(c),0,0,0)

// ---------------------------------------------------------------------------
__global__ __launch_bounds__(256) void k_xconv(const float* __restrict__ in,
                                               f16* __restrict__ o, int n4) {
    const int i = blockIdx.x * 256 + threadIdx.x;
    if (i < n4) {
        const float4 v = ((const float4*)in)[i];
        f16 tmp[4] = {(f16)v.x, (f16)v.y, (f16)v.z, (f16)v.w};
        ((uint2*)o)[i] = *(const uint2*)tmp;
    }
}

// ---------------------------------------------------------------------------
// tiled transpose + fp32->fp16
__global__ __launch_bounds__(256) void k_transpose_h(const float* __restrict__ in,
                                                     f16* __restrict__ out,
                                                     int C, int out_stride, int out_off) {
    __shared__ f16 tile[64][65];
    const int tc = blockIdx.x * 64, tr = blockIdx.y * 64;
    const int tx = threadIdx.x & 63, ty0 = threadIdx.x >> 6;
#pragma unroll
    for (int i = 0; i < 64; i += 4)
        tile[ty0 + i][tx] = (f16)(in[(tr + ty0 + i) * C + tc + tx]);
    __syncthreads();
#pragma unroll
    for (int i = 0; i < 64; i += 4)
        out[(tc + ty0 + i) * out_stride + out_off + tr + tx] = tile[tx][ty0 + i];
}

// tiled transpose + fp32->bf16 (agg only)
__global__ __launch_bounds__(256) void k_transpose_b(const float* __restrict__ in,
                                                     bf16* __restrict__ out,
                                                     int C, int out_stride, int out_off) {
    __shared__ bf16 tile[64][65];
    const int tc = blockIdx.x * 64, tr = blockIdx.y * 64;
    const int tx = threadIdx.x & 63, ty0 = threadIdx.x >> 6;
#pragma unroll
    for (int i = 0; i < 64; i += 4)
        tile[ty0 + i][tx] = __float2bfloat16(in[(tr + ty0 + i) * C + tc + tx]);
    __syncthreads();
#pragma unroll
    for (int i = 0; i < 64; i += 4)
        out[(tc + ty0 + i) * out_stride + out_off + tr + tx] = tile[tx][ty0 + i];
}

// ---------------------------------------------------------------------------
struct AttPtrs { const float* p[12]; };

__global__ __launch_bounds__(256) void k_scal(AttPtrs ap, float* __restrict__ scal) {
    __shared__ float red[256];
    const int tid = threadIdx.x;
    for (int q = 0; q < 6; ++q) {
        const float* l = ap.p[2 * q];
        const float* r = ap.p[2 * q + 1];
        float s = 0.f;
        for (int i = tid; i < 1024; i += 256)
            s += l[i] * r[i];
        red[tid] = s; __syncthreads();
        for (int o = 128; o > 0; o >>= 1) {
            if (tid < o) red[tid] += red[tid + o];
            __syncthreads();
        }
        if (tid == 0) scal[q] = red[0];
        __syncthreads();
    }
}

// ---------------------------------------------------------------------------
// block collectives (256 threads = 4 waves)
__device__ __forceinline__ float wave_sum(float v) {
#pragma unroll
    for (int o = 32; o > 0; o >>= 1) v += __shfl_xor(v, o, 64);
    return v;
}
__device__ __forceinline__ float wave_max(float v) {
#pragma unroll
    for (int o = 32; o > 0; o >>= 1) v = fmaxf(v, __shfl_xor(v, o, 64));
    return v;
}
__device__ __forceinline__ float wave_scan(float v, int lane) {
#pragma unroll
    for (int o = 1; o < 64; o <<= 1) {
        float n = __shfl_up(v, o, 64);
        if (lane >= o) v += n;
    }
    return v;
}
__device__ __forceinline__ float block_sum(float v, float* sm4, int w, int lane) {
    float s = wave_sum(v);
    if (lane == 0) sm4[w] = s;
    __syncthreads();
    float r = sm4[0] + sm4[1] + sm4[2] + sm4[3];
    __syncthreads();
    return r;
}
__device__ __forceinline__ float block_max(float v, float* sm4, int w, int lane) {
    float s = wave_max(v);
    if (lane == 0) sm4[w] = s;
    __syncthreads();
    float r = fmaxf(fmaxf(sm4[0], sm4[1]), fmaxf(sm4[2], sm4[3]));
    __syncthreads();
    return r;
}
__device__ __forceinline__ float block_scan(float v, float* sm4, int w, int lane, float* total) {
    float ws = wave_scan(v, lane);
    if (lane == 63) sm4[w] = ws;
    __syncthreads();
    float base = 0.f;
    if (w > 0) base += sm4[0];
    if (w > 1) base += sm4[1];
    if (w > 2) base += sm4[2];
    *total = sm4[0] + sm4[1] + sm4[2] + sm4[3];
    __syncthreads();
    return base + ws;
}
__device__ __forceinline__ float sigm(float x) { return 1.f / (1.f + __expf(-x)); }

// ---------------------------------------------------------------------------
// sc1 (coherence-point) data path: relaxed agent-scope atomics.
__device__ __forceinline__ u64 ald64(const void* p) {
    return __hip_atomic_load((const u64*)p, __ATOMIC_RELAXED, __HIP_MEMORY_SCOPE_AGENT);
}
__device__ __forceinline__ bf16x8 ald16B(const bf16* p) {
    union { bf16x8 v; u64 u[2]; } r;
    r.u[0] = ald64(p);
    r.u[1] = ald64((const char*)p + 8);
    return r.v;
}
__device__ __forceinline__ f16x8 aldh16B(const f16* p) {
    union { f16x8 v; u64 u[2]; } r;
    r.u[0] = ald64(p);
    r.u[1] = ald64((const char*)p + 8);
    return r.v;
}
__device__ __forceinline__ f32x4 ald_f4(const float* p) {
    union { f32x4 v; u64 u[2]; } r;
    r.u[0] = ald64(p);
    r.u[1] = ald64(p + 2);
    return r.v;
}
__device__ __forceinline__ float ald_f(const float* p) {
    return __hip_atomic_load(p, __ATOMIC_RELAXED, __HIP_MEMORY_SCOPE_AGENT);
}
__device__ __forceinline__ void ast64(void* p, u64 v) {
    __hip_atomic_store((u64*)p, v, __ATOMIC_RELAXED, __HIP_MEMORY_SCOPE_AGENT);
}
__device__ __forceinline__ void ast32(void* p, unsigned v) {
    __hip_atomic_store((unsigned*)p, v, __ATOMIC_RELAXED, __HIP_MEMORY_SCOPE_AGENT);
}
__device__ __forceinline__ void ast_f(float* p, float v) {
    __hip_atomic_store(p, v, __ATOMIC_RELAXED, __HIP_MEMORY_SCOPE_AGENT);
}
__device__ __forceinline__ unsigned h16bits(f16 h) {
    unsigned short s; __builtin_memcpy(&s, &h, 2); return (unsigned)s;
}
__device__ __forceinline__ u64 packf2(float a, float b) {
    union { float f[2]; u64 u; } r; r.f[0] = a; r.f[1] = b; return r.u;
}

// flag barriers, fence-free (see v3 comment)
__device__ __forceinline__ void signal_flag(int* f, int v) {
    __syncthreads();
    if (threadIdx.x == 0)
        __hip_atomic_store(f, v, __ATOMIC_RELAXED, __HIP_MEMORY_SCOPE_AGENT);
}
__device__ __forceinline__ void wait_ge(const int* f, int n, int tgt) {
    if (threadIdx.x < 64) {
        for (;;) {
            int mn = 0x7fffffff;
            for (int i = threadIdx.x; i < n; i += 64) {
                const int v = __hip_atomic_load(f + i * FPAD, __ATOMIC_RELAXED,
                                                __HIP_MEMORY_SCOPE_AGENT);
                mn = v < mn ? v : mn;
            }
            if (__all(mn >= tgt)) break;
            __builtin_amdgcn_s_sleep(1);
        }
    }
    __syncthreads();
}

// swizzled LDS reads
__device__ __forceinline__ bf16x8 lds_rd(const char* s, int nloc, int kb, int rs) {
    return *(const bf16x8*)(s + nloc * rs + (kb ^ ((nloc & 7) << 4)));
}
__device__ __forceinline__ f16x8 lds_rdh(const char* s, int nloc, int kb, int rs) {
    return *(const f16x8*)(s + nloc * rs + (kb ^ ((nloc & 7) << 4)));
}

// ---------------------------------------------------------------------------
__global__ __launch_bounds__(256, 1) void k_persist(
    const f16* __restrict__ xbf, const f16* __restrict__ kt,
    const f16* __restrict__ wrct, const bf16* __restrict__ aggt,
    float* __restrict__ zp, f16* __restrict__ abuf,
    float* __restrict__ c32, bf16* __restrict__ obuf,
    float* __restrict__ pbuf,
    const float* __restrict__ scal, const float* __restrict__ bias,
    float* __restrict__ out, int* __restrict__ ctr)
{
    __shared__ __align__(16) char smem[147456];   // A: 128KB weights + 16KB kt; B: 96KB aggT slice
    __shared__ float sm4[4];

    const int bid = blockIdx.x, tid = threadIdx.x;
    const int w = tid >> 6, lane = tid & 63;
    const int ml = lane & 15, q = lane >> 4;
    int* fA = ctr;            // [160*FPAD] z-partials ready (value t+1)
    int* fB = ctr + 1280;     // [64*FPAD]  O rows ready
    int* fC = ctr + 1792;     // [64*FPAD]  h,c state ready
    int* fP = ctr + 2304;     // [64*FPAD]  f-partials ready

    if (bid < NBLK_A) {
        // =================== role A: z-GEMM partial ====================
        const int cg = bid >> 2;            // col group: cols cg*128..+127
        const int kq = bid & 3;             // K quarter: 0,1=h halves; 2,3=c halves
        const int n0 = cg * 128;
        const int kwbase = (kq < 2) ? kq * 512 : 1024 + (kq - 2) * 512;
        const int kA0 = (kq & 1) * 512;     // offset within h (or c) plane

        // stage weights [128 cols][512 k] f16, swizzled, rs=1024B
        for (int i = 0; i < 32; ++i) {
            const int cid = i * 256 + tid;
            const int row = cid >> 6, k = (cid & 63) * 8;
            f16x8 v = *(const f16x8*)(wrct + (size_t)(n0 + row) * K2 + kwbase + k);
            *(f16x8*)(smem + row * 1024 + ((k * 2) ^ ((row & 7) << 4))) = v;
        }
        // stage kt slab [128 cols][64 k] f16, swizzled, rs=128B
        for (int i = 0; i < 4; ++i) {
            const int cid = i * 256 + tid;
            const int row = cid >> 3, k = (cid & 7) * 8;
            f16x8 v = *(const f16x8*)(kt + (size_t)(n0 + row) * DIM + kq * 64 + k);
            *(f16x8*)(smem + KT_OFF + row * 128 + ((k * 2) ^ ((row & 7) << 4))) = v;
        }
        __syncthreads();

        const int arow = w * 16 + ml;       // this lane's batch row (A-frag row)
        const f16* hP = abuf + (kq < 2 ? 0 : 1) * 65536 + arow * U + kA0;
        const f16* xrow = xbf + (size_t)arow * TSTEPS * DIM;
        float* zpq = zp + (size_t)kq * 64 * N5;
        // only the 32 state stripes covering this block's k-range feed it:
        // h/c cols [ (kq&1)*512, +512 ) -> rb in [ (kq&1)*32, +32 )
        int* fCmy = fC + ((kq & 1) * 32) * FPAD;

        for (int t = 0; t < TSTEPS; ++t) {
            // x loads issued BEFORE the wait (fly during polling)
            const f16x8 ax0 = *(const f16x8*)(xrow + t * DIM + kq * 64 + q * 8);
            const f16x8 ax1 = *(const f16x8*)(xrow + t * DIM + kq * 64 + 32 + q * 8);

            wait_ge(fCmy, 32, t);            // producer stripes of step t-1

            // issue ALL h/c loads at once: 16 x 16B sc1, 32 loads in flight
            f16x8 a[16];
#pragma unroll
            for (int i = 0; i < 16; ++i)
                a[i] = aldh16B(hP + i * 32 + q * 8);

            f32x4 acc[8];
#pragma unroll
            for (int i = 0; i < 8; ++i) acc[i] = (f32x4){0.f, 0.f, 0.f, 0.f};

            // x @ kt: LDS-only operands -> executes under the vmem loads
#pragma unroll
            for (int cx = 0; cx < 2; ++cx) {
                const f16x8 axv = cx ? ax1 : ax0;
#pragma unroll
                for (int ct = 0; ct < 8; ++ct) {
                    const f16x8 b = lds_rdh(smem + KT_OFF, ct * 16 + ml, cx * 64 + q * 16, 128);
                    acc[ct] = MFMA16H(axv, b, acc[ct]);
                }
            }

            // h/c MFMAs (same accumulation order as v7: g asc, c asc)
#pragma unroll
            for (int i = 0; i < 16; ++i) {
                const int g = i >> 1, c = i & 1;
#pragma unroll
                for (int ct = 0; ct < 8; ++ct) {
                    const f16x8 b = lds_rdh(smem, ct * 16 + ml,
                                            g * 128 + c * 64 + q * 16, 1024);
                    acc[ct] = MFMA16H(a[i], b, acc[ct]);
                }
            }

            // ---- epilogue: z partials, lane-pair packed u64 sc1 stores
#pragma unroll
            for (int ct = 0; ct < 8; ++ct)
#pragma unroll
                for (int r = 0; r < 4; ++r) {
                    const float v = acc[ct][r];
                    const float pv = __shfl_xor(v, 1, 64);
                    if (!(ml & 1)) {
                        const int row = w * 16 + q * 4 + r;
                        const int col = n0 + ct * 16 + ml;
                        ast64(&zpq[row * N5 + col], packf2(v, pv));
                    }
                }
            signal_flag(fA + bid * FPAD, t + 1);
        }
    } else {
        // ===== role B: gates (row rb) + agg-GEMM partial + exchange + state =====
        const int rb = bid - NBLK_A;         // also this block's P2 batch row
        const int cg = rb >> 2;              // agg col-group: cols cg*64..+63
        const int kq2 = rb & 3;              // agg K quarter: k kq2*768..+767
        const int nst = cg * 64 + kq2 * 16;  // state stripe: 16 u-cols
        const int KO = kq2 * 768;            // O k-slice base (elements)

        // stage aggT slice [64 cols][768 k] bf16, swizzled, rs=1536B
        for (int i = 0; i < 24; ++i) {
            const int cid = i * 256 + tid;   // 0..6143
            const int nloc = cid / 96, kc = cid - nloc * 96;
            const int k = kc * 8;
            bf16x8 v = *(const bf16x8*)(aggt + (size_t)(cg * 64 + nloc) * 3072 + KO + k);
            *(bf16x8*)(smem + nloc * 1536 + ((k * 2) ^ ((nloc & 7) << 4))) = v;
        }
        __syncthreads();

        const float s_ud = scal[0], s_ur = scal[1], s_ru = scal[2],
                    s_rd = scal[3], s_du = scal[4], s_dr = scal[5];
        const int rowA = w * 16 + ml;
        const bf16* orow = obuf + rowA * 3072 + KO;
        float* cpriv = c32 + rb * 1024;      // block-private [64 rows][16]

        for (int t = 0; t < TSTEPS; ++t) {
            wait_ge(fA, 96, t + 1);          // z cols 0..3071 ready (cg 0..23)
            // ---------------- P2: gates for batch row rb ----------------
            {
                f32x4 zu = {0.f,0.f,0.f,0.f}, zd = {0.f,0.f,0.f,0.f}, zn = {0.f,0.f,0.f,0.f};
#pragma unroll
                for (int kqi = 0; kqi < 4; ++kqi) {
                    const float* bp = zp + (size_t)kqi * 64 * N5 + rb * N5;
                    zu += ald_f4(bp + tid * 4);
                    zd += ald_f4(bp + U + tid * 4);
                    zn += ald_f4(bp + 2 * U + tid * 4);
                }
                zu += ((const f32x4*)bias)[tid];
                zd += ((const f32x4*)(bias + U))[tid];
                zn += ((const f32x4*)(bias + 2 * U))[tid];

                float mup = block_max(fmaxf(fmaxf(zu[0], zu[1]), fmaxf(zu[2], zu[3])), sm4, w, lane);
                const float e0 = __expf(zu[0] - mup), e1 = __expf(zu[1] - mup),
                            e2 = __expf(zu[2] - mup), e3 = __expf(zu[3] - mup);
                float totu;
                float inclu = block_scan(e0 + e1 + e2 + e3, sm4, w, lane, &totu);
                const float exclu = inclu - (e0 + e1 + e2 + e3);
                const float inv_u = 1.f / totu;
                const float u0 = (exclu + e0) * inv_u;
                const float u1 = (exclu + e0 + e1) * inv_u;
                const float u2 = (exclu + e0 + e1 + e2) * inv_u;
                const float u3 = (exclu + e0 + e1 + e2 + e3) * inv_u;

                float mdn = block_max(fmaxf(fmaxf(zd[0], zd[1]), fmaxf(zd[2], zd[3])), sm4, w, lane);
                const float f0 = __expf(zd[0] - mdn), f1 = __expf(zd[1] - mdn),
                            f2 = __expf(zd[2] - mdn), f3 = __expf(zd[3] - mdn);
                float totd;
                float incld = block_scan(f0 + f1 + f2 + f3, sm4, w, lane, &totd);
                const float excld = incld - (f0 + f1 + f2 + f3);
                const float inv_d = 1.f / totd;
                const float d0 = (totd - excld) * inv_d;
                const float d1 = (totd - excld - f0) * inv_d;
                const float d2 = (totd - excld - f0 - f1) * inv_d;
                const float d3 = (totd - excld - f0 - f1 - f2) * inv_d;

                const float du = block_sum(d0 * u0 + d1 * u1 + d2 * u2 + d3 * u3, sm4, w, lane);
                const float ru = block_sum(zn[0] * u0 + zn[1] * u1 + zn[2] * u2 + zn[3] * u3, sm4, w, lane);
                const float dr = block_sum(d0 * zn[0] + d1 * zn[1] + d2 * zn[2] + d3 * zn[3], sm4, w, lane);

                bf16* orw = obuf + rb * 3072;
                const int j0 = tid * 4;
                const float uu[4] = {u0, u1, u2, u3};
                const float dd[4] = {d0, d1, d2, d3};
                const float rr[4] = {zn[0], zn[1], zn[2], zn[3]};
                union { bf16 h[4]; u64 u; } p1, p2, p3;
#pragma unroll
                for (int i = 0; i < 4; ++i) {
                    p1.h[i] = __float2bfloat16(sigm(s_ud * uu[i] * du) + sigm(s_ur * uu[i] * ru));
                    p2.h[i] = __float2bfloat16(sigm(s_ru * rr[i] * ru) + sigm(s_rd * rr[i] * dr));
                    p3.h[i] = __float2bfloat16(sigm(s_du * dd[i] * du) + sigm(s_dr * dd[i] * dr));
                }
                ast64(orw + j0,         p1.u);
                ast64(orw + U + j0,     p2.u);
                ast64(orw + 2 * U + j0, p3.u);
            }
            signal_flag(fB + rb * FPAD, t + 1);

            // z3/z4 (flags 96..159): issue loads now so they fly under fB wait
            wait_ge(fA + 96 * FPAD, 64, t + 1);
            float z3v[4], z4v[4];
            {
                const int col = nst + ml;
                const int r0 = w * 16 + q * 4;
#pragma unroll
                for (int r = 0; r < 4; ++r) {
                    z3v[r] = bias[3 * U + col];
                    z4v[r] = bias[4 * U + col];
#pragma unroll
                    for (int kqi = 0; kqi < 4; ++kqi) {
                        const float* zr = zp + (size_t)kqi * 64 * N5 + (size_t)(r0 + r) * N5;
                        z3v[r] += ald_f(zr + 3 * U + col);
                        z4v[r] += ald_f(zr + 4 * U + col);
                    }
                }
            }
            wait_ge(fB, NBLK_B, t + 1);      // all O rows ready
            // -------- P3 partial: pf = O[:, KO:KO+768] @ aggT-slice --------
            {
                f32x4 acc[4];
#pragma unroll
                for (int i = 0; i < 4; ++i) acc[i] = (f32x4){0.f, 0.f, 0.f, 0.f};
                bf16x8 ob[3][8];
#pragma unroll
                for (int G = 0; G < 3; ++G)
#pragma unroll
                    for (int j = 0; j < 8; ++j)
                        ob[G][j] = ald16B(orow + (G * 8 + j) * 32 + q * 8);
#pragma unroll
                for (int g = 0; g < 3; ++g)
#pragma unroll
                    for (int j = 0; j < 8; ++j) {
                        const int kc = g * 8 + j;
#pragma unroll
                        for (int ct = 0; ct < 4; ++ct) {
                            const bf16x8 b = lds_rd(smem, ct * 16 + ml, kc * 64 + q * 16, 1536);
                            acc[ct] = MFMA16(ob[g][j], b, acc[ct]);
                        }
                    }
                // partial store: pbuf[cg][row][colInCg][kq2], scalar sc1 stores
#pragma unroll
                for (int ct = 0; ct < 4; ++ct)
#pragma unroll
                    for (int r = 0; r < 4; ++r) {
                        const int row = w * 16 + q * 4 + r;
                        ast_f(&pbuf[(((size_t)cg * 64 + row) * 64 + ct * 16 + ml) * 4 + kq2],
                              acc[ct][r]);
                    }
            }
            signal_flag(fP + rb * FPAD, t + 1);
            wait_ge(fP + cg * 4 * FPAD, 4, t + 1);   // siblings' partials ready
            // -------- sum partials (f32x4 gather), state update --------
            float hns[4];
            {
                const int col = nst + ml;
                const int r0 = w * 16 + q * 4;
#pragma unroll
                for (int r = 0; r < 4; ++r) {
                    const int row = r0 + r;
                    const f32x4 pj = ald_f4(&pbuf[(((size_t)cg * 64 + row) * 64 + kq2 * 16 + ml) * 4]);
                    const float s = (pj[0] + pj[1]) + (pj[2] + pj[3]);
                    const float f = sigm(s);
                    const float cold = cpriv[row * 16 + ml];
                    const float cn = f * cold + (1.f - f) * tanhf(z4v[r]);
                    const float hn = z3v[r] * tanhf(cn);
                    cpriv[row * 16 + ml] = cn;
                    hns[r] = hn;
                    const f16 hhb = (f16)hn;
                    const f16 ccb = (f16)cn;
                    unsigned vh = h16bits(hhb), vc = h16bits(ccb);
                    const unsigned ph = (unsigned)__shfl_xor((int)vh, 1, 64);
                    const unsigned pc = (unsigned)__shfl_xor((int)vc, 1, 64);
                    if (!(ml & 1)) {
                        const int eo = row * U + col;
                        ast32((unsigned*)(abuf + 0 * 65536 + eo), vh | (ph << 16));
                        ast32((unsigned*)(abuf + 1 * 65536 + eo), vc | (pc << 16));
                    }
                }
            }
            signal_flag(fC + rb * FPAD, t + 1);
            // out-store AFTER the signal: off the critical vmcnt drain
            {
                const int col = nst + ml;
                const int r0 = w * 16 + q * 4;
#pragma unroll
                for (int r = 0; r < 4; ++r)
                    out[((size_t)(r0 + r) * TSTEPS + t) * U + col] = hns[r];
            }
        }
    }
}

// ---------------------------------------------------------------------------
extern "C" void kernel_launch(void* const* d_in, const int* in_sizes, int n_in,
                              void* d_out, int out_size, void* d_ws, size_t ws_size,
                              hipStream_t stream) {
    (void)in_sizes; (void)n_in; (void)out_size; (void)ws_size;
    const float* x    = (const float*)d_in[0];
    const float* Wk   = (const float*)d_in[1];   // (256,5120)
    const float* Wr   = (const float*)d_in[2];   // (1024,5120)
    const float* Wc   = (const float*)d_in[3];   // (1024,5120)
    const float* bias = (const float*)d_in[4];   // (5120)
    const float* agg  = (const float*)d_in[5];   // (3072,1024)

    char* ws = (char*)d_ws;
    f16*   wrct = (f16*)(ws + OFF_WRC);
    f16*   kt   = (f16*)(ws + OFF_KT);
    bf16*  aggt = (bf16*)(ws + OFF_AGGT);
    f16*   xbf  = (f16*)(ws + OFF_XBF);
    float* zp   = (float*)(ws + OFF_ZP);
    f16*   abuf = (f16*)(ws + OFF_ABUF);
    float* c32  = (float*)(ws + OFF_C32);
    bf16*  obuf = (bf16*)(ws + OFF_OBUF);
    float* pbuf = (float*)(ws + OFF_PB);     // overlays kt (dead after staging)
    float* scal = (float*)(ws + OFF_SCAL);
    int*   ctr  = (int*)(ws + OFF_CTR);
    float* out  = (float*)d_out;

    hipMemsetAsync(abuf, 0, 2 * 65536 * sizeof(f16), stream);
    hipMemsetAsync(c32, 0, BATCH * U * sizeof(float), stream);
    hipMemsetAsync(ctr, 0, 12288, stream);   // flag zone reset each launch

    // one-time conversions / transposes
    k_xconv<<<(BATCH * TSTEPS * DIM / 4 + 255) / 256, 256, 0, stream>>>(x, xbf, BATCH * TSTEPS * DIM / 4);
    k_transpose_h<<<dim3(5120 / 64, 1024 / 64), 256, 0, stream>>>(Wr, wrct, 5120, 2048, 0);
    k_transpose_h<<<dim3(5120 / 64, 1024 / 64), 256, 0, stream>>>(Wc, wrct, 5120, 2048, 1024);
    k_transpose_h<<<dim3(5120 / 64, 256 / 64),  256, 0, stream>>>(Wk, kt,   5120, 256, 0);
    k_transpose_b<<<dim3(1024 / 64, 3072 / 64), 256, 0, stream>>>(agg, aggt, 1024, 3072, 0);

    AttPtrs ap;
    for (int i = 0; i < 12; ++i) ap.p[i] = (const float*)d_in[6 + i];
    k_scal<<<1, 256, 0, stream>>>(ap, scal);

    // the whole recurrence: one persistent launch
    k_persist<<<NBLK, 256, 0, stream>>>(xbf, kt, wrct, aggt, zp, abuf, c32,
                                        obuf, pbuf, scal, bias, out, ctr);
}